// Round 6
// baseline (80.735 us; speedup 1.0000x reference)
//
#include <hip/hip_runtime.h>
#include <math.h>

#define BATCH 4
#define CIN   128
#define CO    64
#define NPIX  4096

typedef unsigned int   uint_t;
typedef unsigned short ushort_t;
typedef __bf16 bfx8 __attribute__((ext_vector_type(8)));
typedef float  f32x4 __attribute__((ext_vector_type(4)));

#define MFMA(a,b,c) __builtin_amdgcn_mfma_f32_16x16x32_bf16((a),(b),(c),0,0,0)
#define BC8(x) __builtin_bit_cast(bfx8,(x))

static __device__ __forceinline__ ushort_t f2bf(float f) {
    uint_t u = __builtin_bit_cast(uint_t, f);
    u = (u + 0x7fffu + ((u >> 16) & 1u)) >> 16;   // RNE
    return (ushort_t)u;
}
static __device__ __forceinline__ float bf2f(ushort_t h) {
    return __builtin_bit_cast(float, (uint_t)h << 16);
}
static __device__ __forceinline__ uint_t pk2(float a, float b) {
    return (uint_t)f2bf(a) | ((uint_t)f2bf(b) << 16);
}
static __device__ __forceinline__ uint_t cvtpk(float lo, float hi) {
    uint_t r;
    asm("v_cvt_pk_bf16_f32 %0, %1, %2" : "=v"(r) : "v"(lo), "v"(hi));
    return r;
}
static __device__ __forceinline__ void gload16(const void* g, void* l) {
    __builtin_amdgcn_global_load_lds(
        (const __attribute__((address_space(1))) void*)g,
        (__attribute__((address_space(3))) void*)l, 16, 0, 0);
}

// ---------------- Kernel 0: convert Wf,Wg,Wh,Wa to bf16 in ws ----------------
__global__ __launch_bounds__(256) void wconv_kernel(
    const float* __restrict__ Wf, const float* __restrict__ Wg,
    const float* __restrict__ Wh, const float* __restrict__ Wa,
    ushort_t* __restrict__ Wb)
{
    int gid = blockIdx.x * 256 + threadIdx.x;
    for (int e = gid; e < 28672; e += 4096) {
        float v;
        if      (e < 8192)  v = Wf[e];
        else if (e < 16384) v = Wg[e - 8192];
        else if (e < 24576) v = Wh[e - 16384];
        else                v = Wa[e - 24576];
        Wb[e] = f2bf(v);
    }
}

// ---------------- Kernel 1: MFMA projections (verified R4, unchanged) ----------------
__global__ __launch_bounds__(256) void proj_kernel(
    const float* __restrict__ x, const ushort_t* __restrict__ Wb,
    const float* __restrict__ bf_, const float* __restrict__ bg_, const float* __restrict__ bh_,
    ushort_t* __restrict__ Q, ushort_t* __restrict__ K, ushort_t* __restrict__ V)
{
    __shared__ ushort_t xs[CIN][70];   // hi
    __shared__ ushort_t xl[CIN][70];   // lo

    int bid = blockIdx.x, b = bid >> 6, n0 = (bid & 63) << 6, t = threadIdx.x;
    int w = t >> 6, lane = t & 63, cl = lane & 15, g = (lane >> 4) & 3;

    const float* xb = x + (size_t)b * CIN * NPIX + n0;
    #pragma unroll
    for (int i = 0; i < 8; ++i) {
        int idx = t + (i << 8);
        int cc = idx >> 4, n4 = idx & 15;
        float4 v = *(const float4*)(xb + (size_t)cc * NPIX + (n4 << 2));
        ushort_t h0 = f2bf(v.x), h1 = f2bf(v.y), h2 = f2bf(v.z), h3 = f2bf(v.w);
        ushort_t* dh = &xs[cc][n4 << 2];
        *(uint_t*)dh       = (uint_t)h0 | ((uint_t)h1 << 16);
        *(uint_t*)(dh + 2) = (uint_t)h2 | ((uint_t)h3 << 16);
        ushort_t* dl = &xl[cc][n4 << 2];
        *(uint_t*)dl       = pk2(v.x - bf2f(h0), v.y - bf2f(h1));
        *(uint_t*)(dl + 2) = pk2(v.z - bf2f(h2), v.w - bf2f(h3));
    }
    __syncthreads();

    uint4 aq[4], al[4];
    int col = (w << 4) + cl;
    #pragma unroll
    for (int ks = 0; ks < 4; ++ks) {
        ushort_t av[8], lv[8];
        #pragma unroll
        for (int j = 0; j < 8; ++j) {
            av[j] = xs[(ks << 5) + (g << 3) + j][col];
            lv[j] = xl[(ks << 5) + (g << 3) + j][col];
        }
        uint4 a, l;
        a.x = (uint_t)av[0] | ((uint_t)av[1] << 16);
        a.y = (uint_t)av[2] | ((uint_t)av[3] << 16);
        a.z = (uint_t)av[4] | ((uint_t)av[5] << 16);
        a.w = (uint_t)av[6] | ((uint_t)av[7] << 16);
        l.x = (uint_t)lv[0] | ((uint_t)lv[1] << 16);
        l.y = (uint_t)lv[2] | ((uint_t)lv[3] << 16);
        l.z = (uint_t)lv[4] | ((uint_t)lv[5] << 16);
        l.w = (uint_t)lv[6] | ((uint_t)lv[7] << 16);
        aq[ks] = a; al[ks] = l;
    }

    const float* bps[3] = {bf_, bg_, bh_};
    int nb = n0 + (w << 4);

    for (int p = 0; p < 3; ++p) {
        const ushort_t* Wp = Wb + p * 8192;
        f32x4 acc[4];
        #pragma unroll
        for (int ot = 0; ot < 4; ++ot) acc[ot] = (f32x4){0.f,0.f,0.f,0.f};
        #pragma unroll
        for (int ks = 0; ks < 4; ++ks) {
            #pragma unroll
            for (int ot = 0; ot < 4; ++ot) {
                uint4 bq = *(const uint4*)(Wp + (((ot << 4) + cl) << 7) + (ks << 5) + (g << 3));
                acc[ot] = MFMA(BC8(aq[ks]), BC8(bq), acc[ot]);
                acc[ot] = MFMA(BC8(al[ks]), BC8(bq), acc[ot]);
            }
        }
        if (p < 2) {
            ushort_t* dst = (p == 0 ? Q : K) + ((size_t)b * NPIX + nb) * CO;
            #pragma unroll
            for (int ot = 0; ot < 4; ++ot) {
                float bias = bps[p][(ot << 4) + cl];
                #pragma unroll
                for (int r = 0; r < 4; ++r)
                    dst[(size_t)((g << 2) + r) * CO + (ot << 4) + cl] = f2bf(acc[ot][r] + bias);
            }
        } else {
            #pragma unroll
            for (int ot = 0; ot < 4; ++ot) {
                float bias = bps[p][(ot << 4) + cl];
                uint2 pk;
                pk.x = pk2(acc[ot][0] + bias, acc[ot][1] + bias);
                pk.y = pk2(acc[ot][2] + bias, acc[ot][3] + bias);
                ushort_t* Vd = V + (size_t)b * CO * NPIX + (size_t)((ot << 4) + cl) * NPIX + nb + (g << 2);
                *(uint2*)Vd = pk;
            }
        }
    }
}

// ---------------- Kernel 2: flash attention, 32q/block, 2 blocks/CU ----------------
// 512 blocks, 512 thr = 8 waves. h = w>>2 (q-group of 16), ws = w&3 (32-key slice).
// Dynamic LDS 74752B:
//   buf0 @0:     K [128][64] swz ^key&7 (16K) | Vt [64][128] swz ^d&7 @16384 (16K)
//   buf1 @32768: same layout
//   P    @65536: per-wave [16q][32k] bf16 pitch 72B (8 x 1152B)
// Staging = global_load_lds, linear LDS dest + pre-swizzled global source.
// Epilogue overlays: mlb/llb @65536 (dead P); Po f32 [32q][64d] @0; Pb bf16 @16384.
#define PREG 65536

__global__ __launch_bounds__(512, 4) void flash_kernel(
    const ushort_t* __restrict__ Q, const ushort_t* __restrict__ K,
    const ushort_t* __restrict__ V, const ushort_t* __restrict__ Wb,
    const float* __restrict__ ba, const float* __restrict__ gamma,
    float* __restrict__ out)
{
    extern __shared__ __align__(16) char smem[];

    int orig = blockIdx.x;
    int bid = ((orig & 7) << 6) | (orig >> 3);      // XCD swizzle: 64 consecutive per XCD
    int b = bid >> 7, n0 = (bid & 127) << 5, t = threadIdx.x;
    int w = t >> 6, lane = t & 63, c = lane & 15, g = (lane >> 4) & 3;
    int h = w >> 2, ws = w & 3;

    const ushort_t* Qb = Q + ((size_t)b * NPIX + n0) * CO;
    const ushort_t* Kb = K + (size_t)b * NPIX * CO;
    const ushort_t* Vb = V + (size_t)b * CO * NPIX;

    // Q fragment: q = 16h + c, d = 32ds + 8g + j
    uint4 qf[2];
    #pragma unroll
    for (int ds = 0; ds < 2; ++ds)
        qf[ds] = *(const uint4*)(Qb + ((h << 4) + c) * CO + (ds << 5) + (g << 3));

    f32x4 oac[4];   // O[d][q], d = 16ds + 4g + r, q = 16h + c
    #pragma unroll
    for (int i = 0; i < 4; ++i) oac[i] = (f32x4){0.f,0.f,0.f,0.f};
    float mreg = -INFINITY, lreg = 0.f;

    char* Pmy = smem + PREG + w * 1152;

    // stage tile kt into buf: linear LDS dest, inverse-swizzled global source
    auto STAGE = [&](char* buf, int kt) {
        #pragma unroll
        for (int i = 0; i < 2; ++i) {
            int cb = (((w << 1) + i) << 6);          // wave-uniform chunk base
            int ci = cb | lane;
            int key = ci >> 3, kc = (ci & 7) ^ (key & 7);
            gload16(Kb + (size_t)((kt << 7) + key) * CO + (kc << 3), buf + (cb << 4));
            int d = ci >> 4, vc = (ci & 15) ^ (d & 7);
            gload16(Vb + (size_t)d * NPIX + (kt << 7) + (vc << 3), buf + 16384 + (cb << 4));
        }
    };

    STAGE(smem, 0);
    __syncthreads();

    int cur = 0;
    for (int kt = 0; kt < 32; ++kt) {
        char* bufc = smem + (cur << 15);
        if (kt + 1 < 32) STAGE(smem + ((cur ^ 1) << 15), kt + 1);

        // ---- QK^T: S[key][q] for 32-key slice ws ----
        f32x4 sac[2];
        sac[0] = (f32x4){0.f,0.f,0.f,0.f};
        sac[1] = (f32x4){0.f,0.f,0.f,0.f};
        __builtin_amdgcn_s_setprio(1);
        #pragma unroll
        for (int s = 0; s < 2; ++s) {
            int key = (ws << 5) + (s << 4) + c;
            int sw = key & 7;
            uint4 kf0 = *(const uint4*)(bufc + (key << 7) + ((g ^ sw) << 4));
            uint4 kf1 = *(const uint4*)(bufc + (key << 7) + (((4 | g) ^ sw) << 4));
            sac[s] = MFMA(BC8(kf0), BC8(qf[0]), sac[s]);
            sac[s] = MFMA(BC8(kf1), BC8(qf[1]), sac[s]);
        }
        __builtin_amdgcn_s_setprio(0);

        // ---- online softmax with defer-max (THR=8) ----
        float mx = sac[0][0];
        #pragma unroll
        for (int j = 1; j < 4; ++j) mx = fmaxf(mx, sac[0][j]);
        #pragma unroll
        for (int j = 0; j < 4; ++j) mx = fmaxf(mx, sac[1][j]);
        mx = fmaxf(mx, __shfl_xor(mx, 16));
        mx = fmaxf(mx, __shfl_xor(mx, 32));
        if (!__all(mx <= mreg + 8.f)) {
            float mn = fmaxf(mreg, mx);
            float r  = __expf(mreg - mn);
            lreg *= r;
            #pragma unroll
            for (int ds = 0; ds < 4; ++ds) oac[ds] *= r;
            mreg = mn;
        }
        float ps[8], ls = 0.f;
        #pragma unroll
        for (int s = 0; s < 2; ++s)
            #pragma unroll
            for (int j = 0; j < 4; ++j) {
                float p = __expf(sac[s][j] - mreg);
                ps[(s << 2) + j] = p; ls += p;
            }
        ls += __shfl_xor(ls, 16);
        ls += __shfl_xor(ls, 32);
        lreg += ls;
        #pragma unroll
        for (int s = 0; s < 2; ++s) {
            uint2 pk;
            pk.x = cvtpk(ps[(s << 2) + 0], ps[(s << 2) + 1]);
            pk.y = cvtpk(ps[(s << 2) + 2], ps[(s << 2) + 3]);
            *(uint2*)(Pmy + c * 72 + (s << 5) + (g << 3)) = pk;
        }

        // ---- PV over the wave's 32-key slice ----
        uint4 vf[4];
        #pragma unroll
        for (int ds = 0; ds < 4; ++ds) {
            int d = (ds << 4) + c;
            vf[ds] = *(const uint4*)(bufc + 16384 + (d << 8) + ((((ws << 2) | g) ^ (d & 7)) << 4));
        }
        uint4 pf = *(const uint4*)(Pmy + c * 72 + (g << 4));
        __builtin_amdgcn_s_setprio(1);
        #pragma unroll
        for (int ds = 0; ds < 4; ++ds)
            oac[ds] = MFMA(BC8(vf[ds]), BC8(pf), oac[ds]);
        __builtin_amdgcn_s_setprio(0);

        __syncthreads();
        cur ^= 1;
    }

    // ---- stats exchange ----
    float* mlb = (float*)(smem + PREG);          // [8 waves][16 q]
    float* llb = (float*)(smem + PREG + 512);
    if (lane < 16) {
        mlb[(w << 4) + lane] = mreg;
        llb[(w << 4) + lane] = lreg;
    }
    __syncthreads();

    int base = h << 2;
    float m0 = mlb[((base + 0) << 4) + c], m1 = mlb[((base + 1) << 4) + c];
    float m2 = mlb[((base + 2) << 4) + c], m3 = mlb[((base + 3) << 4) + c];
    float M  = fmaxf(fmaxf(m0, m1), fmaxf(m2, m3));
    float a0 = __expf(m0 - M), a1 = __expf(m1 - M), a2 = __expf(m2 - M), a3 = __expf(m3 - M);
    float L  = a0 * llb[((base + 0) << 4) + c] + a1 * llb[((base + 1) << 4) + c]
             + a2 * llb[((base + 2) << 4) + c] + a3 * llb[((base + 3) << 4) + c];
    float aw = (ws == 0) ? a0 : (ws == 1) ? a1 : (ws == 2) ? a2 : a3;
    float fac = aw / L;
    #pragma unroll
    for (int ds = 0; ds < 4; ++ds) oac[ds] *= fac;

    // ---- accumulate scaled partials into Po f32 @0, rounds ws = 0,1,2 ----
    for (int r = 0; r < 3; ++r) {
        if (ws == r) {
            #pragma unroll
            for (int ds = 0; ds < 4; ++ds) {
                int q = (h << 4) + c;
                int off = (q << 8) + ((((ds << 2) | g) ^ (q & 7)) << 4);
                f32x4 v = oac[ds];
                if (r > 0) v += *(const f32x4*)(smem + off);
                *(f32x4*)(smem + off) = v;
            }
        }
        __syncthreads();
    }
    // round 3: final add -> bf16 Pb @16384 ([32q][72] ushort, pitch 144B)
    ushort_t* Pb = (ushort_t*)(smem + 16384);
    if (ws == 3) {
        #pragma unroll
        for (int ds = 0; ds < 4; ++ds) {
            int q = (h << 4) + c;
            int off = (q << 8) + ((((ds << 2) | g) ^ (q & 7)) << 4);
            f32x4 v = oac[ds] + *(const f32x4*)(smem + off);
            uint2 pk;
            pk.x = pk2(v[0], v[1]);
            pk.y = pk2(v[2], v[3]);
            *(uint2*)(Pb + q * 72 + (ds << 4) + (g << 2)) = pk;
        }
    }
    __syncthreads();

    // ---- fused outconv: out[o][q] = gamma*(Wa[o][:] . O_att[:][q] + ba[o]) ----
    const ushort_t* Wab = Wb + 24576;
    float gm = gamma[0];
    int ot = w >> 1, qt = w & 1;
    f32x4 acc2 = (f32x4){0.f,0.f,0.f,0.f};
    #pragma unroll
    for (int ks = 0; ks < 2; ++ks) {
        uint4 af  = *(const uint4*)(Wab + (((ot << 4) + c) << 6) + (ks << 5) + (g << 3));
        uint4 pfq = *(const uint4*)((char*)Pb + (((qt << 4) + c)) * 144 + (ks << 6) + (g << 4));
        acc2 = MFMA(BC8(af), BC8(pfq), acc2);
    }
    float* ob = out + (size_t)b * CO * NPIX + n0;
    #pragma unroll
    for (int r = 0; r < 4; ++r) {
        int o = (ot << 4) + (g << 2) + r;
        ob[(size_t)o * NPIX + (qt << 4) + c] = gm * (acc2[r] + ba[o]);
    }
}

extern "C" void kernel_launch(void* const* d_in, const int* in_sizes, int n_in,
                              void* d_out, int out_size, void* d_ws, size_t ws_size,
                              hipStream_t stream) {
    const float* x     = (const float*)d_in[0];
    const float* Wf    = (const float*)d_in[1];
    const float* bf_   = (const float*)d_in[2];
    const float* Wg    = (const float*)d_in[3];
    const float* bg_   = (const float*)d_in[4];
    const float* Wh    = (const float*)d_in[5];
    const float* bh_   = (const float*)d_in[6];
    const float* Wa    = (const float*)d_in[7];
    const float* ba    = (const float*)d_in[8];
    const float* gamma = (const float*)d_in[9];
    float* out = (float*)d_out;

    ushort_t* Wb = (ushort_t*)d_ws;                               // 57344 B
    const size_t matb = (size_t)BATCH * NPIX * CO;                // 1M elems
    ushort_t* Q = (ushort_t*)((char*)d_ws + 65536);               // 2 MB
    ushort_t* K = Q + matb;                                       // 2 MB
    ushort_t* V = K + matb;                                       // 2 MB (transposed [B][64][N])

    wconv_kernel<<<16, 256, 0, stream>>>(Wf, Wg, Wh, Wa, Wb);
    proj_kernel<<<BATCH * (NPIX / 64), 256, 0, stream>>>(x, Wb, bf_, bg_, bh_, Q, K, V);
    flash_kernel<<<BATCH * (NPIX / 32), 512, 74752, stream>>>(Q, K, V, Wb, ba, gamma, out);
}

// Round 7
// 75.353 us; speedup vs baseline: 1.0714x; 1.0714x over previous
//
#include <hip/hip_runtime.h>
#include <math.h>

#define BATCH 4
#define CIN   128
#define CO    64
#define NPIX  4096

typedef unsigned int   uint_t;
typedef unsigned short ushort_t;
typedef __bf16 bfx8 __attribute__((ext_vector_type(8)));
typedef float  f32x4 __attribute__((ext_vector_type(4)));

#define MFMA(a,b,c) __builtin_amdgcn_mfma_f32_16x16x32_bf16((a),(b),(c),0,0,0)
#define BC8(x) __builtin_bit_cast(bfx8,(x))

static __device__ __forceinline__ ushort_t f2bf(float f) {
    uint_t u = __builtin_bit_cast(uint_t, f);
    u = (u + 0x7fffu + ((u >> 16) & 1u)) >> 16;   // RNE
    return (ushort_t)u;
}
static __device__ __forceinline__ float bf2f(ushort_t h) {
    return __builtin_bit_cast(float, (uint_t)h << 16);
}
static __device__ __forceinline__ uint_t pk2(float a, float b) {
    return (uint_t)f2bf(a) | ((uint_t)f2bf(b) << 16);
}
static __device__ __forceinline__ uint_t cvtpk(float lo, float hi) {
    uint_t r;
    asm("v_cvt_pk_bf16_f32 %0, %1, %2" : "=v"(r) : "v"(lo), "v"(hi));
    return r;
}
static __device__ __forceinline__ void gload16(const void* g, void* l) {
    __builtin_amdgcn_global_load_lds(
        (const __attribute__((address_space(1))) void*)g,
        (__attribute__((address_space(3))) void*)l, 16, 0, 0);
}

// ---------------- Kernel 0: convert Wf,Wg,Wh,Wa to bf16 in ws ----------------
__global__ __launch_bounds__(256) void wconv_kernel(
    const float* __restrict__ Wf, const float* __restrict__ Wg,
    const float* __restrict__ Wh, const float* __restrict__ Wa,
    ushort_t* __restrict__ Wb)
{
    int gid = blockIdx.x * 256 + threadIdx.x;
    for (int e = gid; e < 28672; e += 4096) {
        float v;
        if      (e < 8192)  v = Wf[e];
        else if (e < 16384) v = Wg[e - 8192];
        else if (e < 24576) v = Wh[e - 16384];
        else                v = Wa[e - 24576];
        Wb[e] = f2bf(v);
    }
}

// ---------------- Kernel 1: MFMA projections (verified R4, unchanged) ----------------
__global__ __launch_bounds__(256) void proj_kernel(
    const float* __restrict__ x, const ushort_t* __restrict__ Wb,
    const float* __restrict__ bf_, const float* __restrict__ bg_, const float* __restrict__ bh_,
    ushort_t* __restrict__ Q, ushort_t* __restrict__ K, ushort_t* __restrict__ V)
{
    __shared__ ushort_t xs[CIN][70];   // hi
    __shared__ ushort_t xl[CIN][70];   // lo

    int bid = blockIdx.x, b = bid >> 6, n0 = (bid & 63) << 6, t = threadIdx.x;
    int w = t >> 6, lane = t & 63, cl = lane & 15, g = (lane >> 4) & 3;

    const float* xb = x + (size_t)b * CIN * NPIX + n0;
    #pragma unroll
    for (int i = 0; i < 8; ++i) {
        int idx = t + (i << 8);
        int cc = idx >> 4, n4 = idx & 15;
        float4 v = *(const float4*)(xb + (size_t)cc * NPIX + (n4 << 2));
        ushort_t h0 = f2bf(v.x), h1 = f2bf(v.y), h2 = f2bf(v.z), h3 = f2bf(v.w);
        ushort_t* dh = &xs[cc][n4 << 2];
        *(uint_t*)dh       = (uint_t)h0 | ((uint_t)h1 << 16);
        *(uint_t*)(dh + 2) = (uint_t)h2 | ((uint_t)h3 << 16);
        ushort_t* dl = &xl[cc][n4 << 2];
        *(uint_t*)dl       = pk2(v.x - bf2f(h0), v.y - bf2f(h1));
        *(uint_t*)(dl + 2) = pk2(v.z - bf2f(h2), v.w - bf2f(h3));
    }
    __syncthreads();

    uint4 aq[4], al[4];
    int col = (w << 4) + cl;
    #pragma unroll
    for (int ks = 0; ks < 4; ++ks) {
        ushort_t av[8], lv[8];
        #pragma unroll
        for (int j = 0; j < 8; ++j) {
            av[j] = xs[(ks << 5) + (g << 3) + j][col];
            lv[j] = xl[(ks << 5) + (g << 3) + j][col];
        }
        uint4 a, l;
        a.x = (uint_t)av[0] | ((uint_t)av[1] << 16);
        a.y = (uint_t)av[2] | ((uint_t)av[3] << 16);
        a.z = (uint_t)av[4] | ((uint_t)av[5] << 16);
        a.w = (uint_t)av[6] | ((uint_t)av[7] << 16);
        l.x = (uint_t)lv[0] | ((uint_t)lv[1] << 16);
        l.y = (uint_t)lv[2] | ((uint_t)lv[3] << 16);
        l.z = (uint_t)lv[4] | ((uint_t)lv[5] << 16);
        l.w = (uint_t)lv[6] | ((uint_t)lv[7] << 16);
        aq[ks] = a; al[ks] = l;
    }

    const float* bps[3] = {bf_, bg_, bh_};
    int nb = n0 + (w << 4);

    for (int p = 0; p < 3; ++p) {
        const ushort_t* Wp = Wb + p * 8192;
        f32x4 acc[4];
        #pragma unroll
        for (int ot = 0; ot < 4; ++ot) acc[ot] = (f32x4){0.f,0.f,0.f,0.f};
        #pragma unroll
        for (int ks = 0; ks < 4; ++ks) {
            #pragma unroll
            for (int ot = 0; ot < 4; ++ot) {
                uint4 bq = *(const uint4*)(Wp + (((ot << 4) + cl) << 7) + (ks << 5) + (g << 3));
                acc[ot] = MFMA(BC8(aq[ks]), BC8(bq), acc[ot]);
                acc[ot] = MFMA(BC8(al[ks]), BC8(bq), acc[ot]);
            }
        }
        if (p < 2) {
            ushort_t* dst = (p == 0 ? Q : K) + ((size_t)b * NPIX + nb) * CO;
            #pragma unroll
            for (int ot = 0; ot < 4; ++ot) {
                float bias = bps[p][(ot << 4) + cl];
                #pragma unroll
                for (int r = 0; r < 4; ++r)
                    dst[(size_t)((g << 2) + r) * CO + (ot << 4) + cl] = f2bf(acc[ot][r] + bias);
            }
        } else {
            #pragma unroll
            for (int ot = 0; ot < 4; ++ot) {
                float bias = bps[p][(ot << 4) + cl];
                uint2 pk;
                pk.x = pk2(acc[ot][0] + bias, acc[ot][1] + bias);
                pk.y = pk2(acc[ot][2] + bias, acc[ot][3] + bias);
                ushort_t* Vd = V + (size_t)b * CO * NPIX + (size_t)((ot << 4) + cl) * NPIX + nb + (g << 2);
                *(uint2*)Vd = pk;
            }
        }
    }
}

// ---------------- Kernel 2: flash attention, 3-buffer ring + counted vmcnt ----------------
// 256 blocks, 512 thr = 8 waves. h = w>>2 (q-half: 32 q), ws = w&3 (32-key slice).
// Dynamic LDS 118784B:
//   buf[i] @ i*32768 (i=0,1,2): K [128][64] swz ^key&7 (16K) | Vt [64][128] swz ^d&7 (16K)
//   P @98304: per-wave [32q][32k] bf16 pitch 80B (8 x 2560B)
// Ring schedule: iter t computes buf[t%3], issues STAGE(t+2) into buf[(t+2)%3],
// ends with s_waitcnt vmcnt(4) (t+1's loads landed; t+2's stay in flight) + raw s_barrier.
// Safety: STAGE at iter t targets the buffer last read at iter t-1 (barrier t-1 protects);
// its reads at t+2 are covered by vmcnt wait at t+1.
// Epilogue overlays: mlb/llb @98304 (dead P); Po f32 @0; Pb bf16 @16384.
#define PREG 98304

__global__ __launch_bounds__(512, 1) void flash_kernel(
    const ushort_t* __restrict__ Q, const ushort_t* __restrict__ K,
    const ushort_t* __restrict__ V, const ushort_t* __restrict__ Wb,
    const float* __restrict__ ba, const float* __restrict__ gamma,
    float* __restrict__ out)
{
    extern __shared__ __align__(16) char smem[];

    int orig = blockIdx.x;
    int bid = ((orig & 7) << 5) | (orig >> 3);      // XCD swizzle: 2 XCDs per batch
    int b = bid >> 6, n0 = (bid & 63) << 6, t = threadIdx.x;
    int w = t >> 6, lane = t & 63, c = lane & 15, g = (lane >> 4) & 3;
    int h = w >> 2, ws = w & 3;

    const ushort_t* Qb = Q + ((size_t)b * NPIX + n0) * CO;
    const ushort_t* Kb = K + (size_t)b * NPIX * CO;
    const ushort_t* Vb = V + (size_t)b * CO * NPIX;

    uint4 qf[2][2];
    #pragma unroll
    for (int qs = 0; qs < 2; ++qs)
        #pragma unroll
        for (int ds = 0; ds < 2; ++ds)
            qf[qs][ds] = *(const uint4*)(Qb + ((h << 5) + (qs << 4) + c) * CO + (ds << 5) + (g << 3));

    f32x4 oac[4][2];
    #pragma unroll
    for (int i = 0; i < 4; ++i)
        #pragma unroll
        for (int j = 0; j < 2; ++j) oac[i][j] = (f32x4){0.f,0.f,0.f,0.f};
    float mreg[2] = {-INFINITY, -INFINITY};
    float lreg[2] = {0.f, 0.f};

    char* Pmy = smem + PREG + w * 2560;

    // stage tile kt into buf: linear LDS dest, inverse-swizzled global source
    auto STAGE = [&](char* buf, int kt) {
        #pragma unroll
        for (int i = 0; i < 2; ++i) {
            int cb = (((w << 1) + i) << 6);          // wave-uniform chunk base
            int ci = cb | lane;
            int key = ci >> 3, kc = (ci & 7) ^ (key & 7);
            gload16(Kb + (size_t)((kt << 7) + key) * CO + (kc << 3), buf + (cb << 4));
            int d = ci >> 4, vc = (ci & 15) ^ (d & 7);
            gload16(Vb + (size_t)d * NPIX + (kt << 7) + (vc << 3), buf + 16384 + (cb << 4));
        }
    };

    // prologue: stage tiles 0 and 1; wait for tile 0 only (tile 1 stays in flight)
    STAGE(smem, 0);
    STAGE(smem + 32768, 1);
    asm volatile("s_waitcnt vmcnt(4)" ::: "memory");
    __builtin_amdgcn_s_barrier();

    int bc = 0;
    for (int kt = 0; kt < 32; ++kt) {
        char* bufc = smem + bc * 32768;
        if (kt < 30) {
            int bn = bc + 2; if (bn >= 3) bn -= 3;
            STAGE(smem + bn * 32768, kt + 2);
        }

        // ---- QK^T: S[key][q] for 32-key slice ws ----
        f32x4 sac[2][2];
        #pragma unroll
        for (int s = 0; s < 2; ++s)
            #pragma unroll
            for (int qs = 0; qs < 2; ++qs) sac[s][qs] = (f32x4){0.f,0.f,0.f,0.f};
        __builtin_amdgcn_s_setprio(1);
        #pragma unroll
        for (int s = 0; s < 2; ++s) {
            int key = (ws << 5) + (s << 4) + c;
            int sw = key & 7;
            uint4 kf0 = *(const uint4*)(bufc + (key << 7) + ((g ^ sw) << 4));
            uint4 kf1 = *(const uint4*)(bufc + (key << 7) + (((4 | g) ^ sw) << 4));
            #pragma unroll
            for (int qs = 0; qs < 2; ++qs) {
                sac[s][qs] = MFMA(BC8(kf0), BC8(qf[qs][0]), sac[s][qs]);
                sac[s][qs] = MFMA(BC8(kf1), BC8(qf[qs][1]), sac[s][qs]);
            }
        }
        __builtin_amdgcn_s_setprio(0);

        // ---- online softmax with defer-max (THR=8) ----
        float mx[2], ps[2][8];
        #pragma unroll
        for (int qs = 0; qs < 2; ++qs) {
            float v = sac[0][qs][0];
            #pragma unroll
            for (int j = 1; j < 4; ++j) v = fmaxf(v, sac[0][qs][j]);
            #pragma unroll
            for (int j = 0; j < 4; ++j) v = fmaxf(v, sac[1][qs][j]);
            v = fmaxf(v, __shfl_xor(v, 16));
            v = fmaxf(v, __shfl_xor(v, 32));
            mx[qs] = v;
        }
        bool defer = (mx[0] <= mreg[0] + 8.f) && (mx[1] <= mreg[1] + 8.f);
        if (!__all(defer)) {
            #pragma unroll
            for (int qs = 0; qs < 2; ++qs) {
                float mn = fmaxf(mreg[qs], mx[qs]);
                float r  = __expf(mreg[qs] - mn);
                lreg[qs] *= r;
                #pragma unroll
                for (int ds = 0; ds < 4; ++ds) oac[ds][qs] *= r;
                mreg[qs] = mn;
            }
        }
        #pragma unroll
        for (int qs = 0; qs < 2; ++qs) {
            float ls = 0.f;
            #pragma unroll
            for (int s = 0; s < 2; ++s)
                #pragma unroll
                for (int j = 0; j < 4; ++j) {
                    float p = __expf(sac[s][qs][j] - mreg[qs]);
                    ps[qs][(s << 2) + j] = p; ls += p;
                }
            ls += __shfl_xor(ls, 16);
            ls += __shfl_xor(ls, 32);
            lreg[qs] += ls;
            int ql = (qs << 4) + c;
            #pragma unroll
            for (int s = 0; s < 2; ++s) {
                uint2 pk;
                pk.x = cvtpk(ps[qs][(s << 2) + 0], ps[qs][(s << 2) + 1]);
                pk.y = cvtpk(ps[qs][(s << 2) + 2], ps[qs][(s << 2) + 3]);
                *(uint2*)(Pmy + ql * 80 + (s << 5) + (g << 3)) = pk;
            }
        }

        // ---- PV over the wave's 32-key slice ----
        uint4 vf[4], pf[2];
        #pragma unroll
        for (int ds = 0; ds < 4; ++ds) {
            int d = (ds << 4) + c;
            vf[ds] = *(const uint4*)(bufc + 16384 + (d << 8) + ((((ws << 2) | g) ^ (d & 7)) << 4));
        }
        #pragma unroll
        for (int qs = 0; qs < 2; ++qs)
            pf[qs] = *(const uint4*)(Pmy + ((qs << 4) + c) * 80 + (g << 4));
        __builtin_amdgcn_s_setprio(1);
        #pragma unroll
        for (int ds = 0; ds < 4; ++ds)
            #pragma unroll
            for (int qs = 0; qs < 2; ++qs)
                oac[ds][qs] = MFMA(BC8(vf[ds]), BC8(pf[qs]), oac[ds][qs]);
        __builtin_amdgcn_s_setprio(0);

        // counted wait: t+1's loads landed, t+2's stay in flight across the barrier
        if (kt < 30) asm volatile("s_waitcnt vmcnt(4)" ::: "memory");
        else         asm volatile("s_waitcnt vmcnt(0)" ::: "memory");
        __builtin_amdgcn_s_barrier();
        if (++bc == 3) bc = 0;
    }

    // ---- stats exchange ----
    float* mlb = (float*)(smem + PREG);
    float* llb = (float*)(smem + PREG + 2048);
    if (lane < 16) {
        #pragma unroll
        for (int qs = 0; qs < 2; ++qs) {
            mlb[(w << 6) + (h << 5) + (qs << 4) + lane] = mreg[qs];
            llb[(w << 6) + (h << 5) + (qs << 4) + lane] = lreg[qs];
        }
    }
    __syncthreads();

    float fac[2];
    #pragma unroll
    for (int qs = 0; qs < 2; ++qs) {
        int q = (h << 5) + (qs << 4) + c;
        int base = h << 2;
        float m0 = mlb[((base + 0) << 6) + q], m1 = mlb[((base + 1) << 6) + q];
        float m2 = mlb[((base + 2) << 6) + q], m3 = mlb[((base + 3) << 6) + q];
        float M  = fmaxf(fmaxf(m0, m1), fmaxf(m2, m3));
        float a0 = __expf(m0 - M), a1 = __expf(m1 - M), a2 = __expf(m2 - M), a3 = __expf(m3 - M);
        float L  = a0 * llb[((base + 0) << 6) + q] + a1 * llb[((base + 1) << 6) + q]
                 + a2 * llb[((base + 2) << 6) + q] + a3 * llb[((base + 3) << 6) + q];
        float aw = (ws == 0) ? a0 : (ws == 1) ? a1 : (ws == 2) ? a2 : a3;
        fac[qs] = aw / L;
    }
    #pragma unroll
    for (int ds = 0; ds < 4; ++ds)
        #pragma unroll
        for (int qs = 0; qs < 2; ++qs) oac[ds][qs] *= fac[qs];

    // ---- accumulate scaled partials into Po f32 @0, rounds ws = 0,1,2 ----
    for (int r = 0; r < 3; ++r) {
        if (ws == r) {
            #pragma unroll
            for (int ds = 0; ds < 4; ++ds)
                #pragma unroll
                for (int qs = 0; qs < 2; ++qs) {
                    int q = (h << 5) + (qs << 4) + c;
                    int off = (q << 8) + ((((ds << 2) | g) ^ (q & 7)) << 4);
                    f32x4 v = oac[ds][qs];
                    if (r > 0) v += *(const f32x4*)(smem + off);
                    *(f32x4*)(smem + off) = v;
                }
        }
        __syncthreads();
    }
    // round 3: final add -> bf16 Pb @16384
    ushort_t* Pb = (ushort_t*)(smem + 16384);
    if (ws == 3) {
        #pragma unroll
        for (int ds = 0; ds < 4; ++ds)
            #pragma unroll
            for (int qs = 0; qs < 2; ++qs) {
                int q = (h << 5) + (qs << 4) + c;
                int off = (q << 8) + ((((ds << 2) | g) ^ (q & 7)) << 4);
                f32x4 v = oac[ds][qs] + *(const f32x4*)(smem + off);
                uint2 pk;
                pk.x = pk2(v[0], v[1]);
                pk.y = pk2(v[2], v[3]);
                *(uint2*)(Pb + q * 72 + (ds << 4) + (g << 2)) = pk;
            }
    }
    __syncthreads();

    // ---- fused outconv: out[o][q] = gamma*(Wa[o][:] . Pb[q][:] + ba[o]) ----
    const ushort_t* Wab = Wb + 24576;
    float gm = gamma[0];
    int ot = w >> 1, qtb = (w & 1) << 1;
    f32x4 acc2[2] = {(f32x4){0.f,0.f,0.f,0.f}, (f32x4){0.f,0.f,0.f,0.f}};
    #pragma unroll
    for (int ks = 0; ks < 2; ++ks) {
        uint4 af = *(const uint4*)(Wab + (((ot << 4) + c) << 6) + (ks << 5) + (g << 3));
        #pragma unroll
        for (int i = 0; i < 2; ++i) {
            uint4 pfq = *(const uint4*)((char*)Pb + (((qtb + i) << 4) + c) * 144 + (ks << 6) + (g << 4));
            acc2[i] = MFMA(BC8(af), BC8(pfq), acc2[i]);
        }
    }
    float* ob = out + (size_t)b * CO * NPIX + n0;
    #pragma unroll
    for (int r = 0; r < 4; ++r) {
        int o = (ot << 4) + (g << 2) + r;
        float bias = ba[o];
        #pragma unroll
        for (int i = 0; i < 2; ++i)
            ob[(size_t)o * NPIX + ((qtb + i) << 4) + c] = gm * (acc2[i][r] + bias);
    }
}

extern "C" void kernel_launch(void* const* d_in, const int* in_sizes, int n_in,
                              void* d_out, int out_size, void* d_ws, size_t ws_size,
                              hipStream_t stream) {
    const float* x     = (const float*)d_in[0];
    const float* Wf    = (const float*)d_in[1];
    const float* bf_   = (const float*)d_in[2];
    const float* Wg    = (const float*)d_in[3];
    const float* bg_   = (const float*)d_in[4];
    const float* Wh    = (const float*)d_in[5];
    const float* bh_   = (const float*)d_in[6];
    const float* Wa    = (const float*)d_in[7];
    const float* ba    = (const float*)d_in[8];
    const float* gamma = (const float*)d_in[9];
    float* out = (float*)d_out;

    ushort_t* Wb = (ushort_t*)d_ws;                               // 57344 B
    const size_t matb = (size_t)BATCH * NPIX * CO;                // 1M elems
    ushort_t* Q = (ushort_t*)((char*)d_ws + 65536);               // 2 MB
    ushort_t* K = Q + matb;                                       // 2 MB
    ushort_t* V = K + matb;                                       // 2 MB (transposed [B][64][N])

    wconv_kernel<<<16, 256, 0, stream>>>(Wf, Wg, Wh, Wa, Wb);
    proj_kernel<<<BATCH * (NPIX / 64), 256, 0, stream>>>(x, Wb, bf_, bg_, bh_, Q, K, V);
    flash_kernel<<<BATCH * (NPIX / 64), 512, 118784, stream>>>(Q, K, V, Wb, ba, gamma, out);
}

// Round 8
// 73.196 us; speedup vs baseline: 1.1030x; 1.0295x over previous
//
#include <hip/hip_runtime.h>
#include <math.h>

#define BATCH 4
#define CIN   128
#define CO    64
#define NPIX  4096
#define LOG2E 1.4426950408889634f

typedef unsigned int   uint_t;
typedef unsigned short ushort_t;
typedef __bf16 bfx8 __attribute__((ext_vector_type(8)));
typedef float  f32x4 __attribute__((ext_vector_type(4)));

#define MFMA(a,b,c) __builtin_amdgcn_mfma_f32_16x16x32_bf16((a),(b),(c),0,0,0)
#define BC8(x) __builtin_bit_cast(bfx8,(x))

#if __has_builtin(__builtin_amdgcn_exp2f)
#define EXP2(x) __builtin_amdgcn_exp2f(x)
#else
#define EXP2(x) exp2f(x)
#endif

static __device__ __forceinline__ ushort_t f2bf(float f) {
    uint_t u = __builtin_bit_cast(uint_t, f);
    u = (u + 0x7fffu + ((u >> 16) & 1u)) >> 16;   // RNE
    return (ushort_t)u;
}
static __device__ __forceinline__ float bf2f(ushort_t h) {
    return __builtin_bit_cast(float, (uint_t)h << 16);
}
static __device__ __forceinline__ uint_t pk2(float a, float b) {
    return (uint_t)f2bf(a) | ((uint_t)f2bf(b) << 16);
}
static __device__ __forceinline__ uint_t cvtpk(float lo, float hi) {
    uint_t r;
    asm("v_cvt_pk_bf16_f32 %0, %1, %2" : "=v"(r) : "v"(lo), "v"(hi));
    return r;
}
static __device__ __forceinline__ void gload16(const void* g, void* l) {
    __builtin_amdgcn_global_load_lds(
        (const __attribute__((address_space(1))) void*)g,
        (__attribute__((address_space(3))) void*)l, 16, 0, 0);
}

// ---------------- Kernel 0: convert Wf,Wg,Wh,Wa to bf16 in ws ----------------
__global__ __launch_bounds__(256) void wconv_kernel(
    const float* __restrict__ Wf, const float* __restrict__ Wg,
    const float* __restrict__ Wh, const float* __restrict__ Wa,
    ushort_t* __restrict__ Wb)
{
    int gid = blockIdx.x * 256 + threadIdx.x;
    for (int e = gid; e < 28672; e += 4096) {
        float v;
        if      (e < 8192)  v = Wf[e];
        else if (e < 16384) v = Wg[e - 8192];
        else if (e < 24576) v = Wh[e - 16384];
        else                v = Wa[e - 24576];
        Wb[e] = f2bf(v);
    }
}

// ---------------- Kernel 1: MFMA projections (R4-verified; Q scaled by log2e) ----------------
__global__ __launch_bounds__(256) void proj_kernel(
    const float* __restrict__ x, const ushort_t* __restrict__ Wb,
    const float* __restrict__ bf_, const float* __restrict__ bg_, const float* __restrict__ bh_,
    ushort_t* __restrict__ Q, ushort_t* __restrict__ K, ushort_t* __restrict__ V)
{
    __shared__ ushort_t xs[CIN][70];   // hi
    __shared__ ushort_t xl[CIN][70];   // lo

    int bid = blockIdx.x, b = bid >> 6, n0 = (bid & 63) << 6, t = threadIdx.x;
    int w = t >> 6, lane = t & 63, cl = lane & 15, g = (lane >> 4) & 3;

    const float* xb = x + (size_t)b * CIN * NPIX + n0;
    #pragma unroll
    for (int i = 0; i < 8; ++i) {
        int idx = t + (i << 8);
        int cc = idx >> 4, n4 = idx & 15;
        float4 v = *(const float4*)(xb + (size_t)cc * NPIX + (n4 << 2));
        ushort_t h0 = f2bf(v.x), h1 = f2bf(v.y), h2 = f2bf(v.z), h3 = f2bf(v.w);
        ushort_t* dh = &xs[cc][n4 << 2];
        *(uint_t*)dh       = (uint_t)h0 | ((uint_t)h1 << 16);
        *(uint_t*)(dh + 2) = (uint_t)h2 | ((uint_t)h3 << 16);
        ushort_t* dl = &xl[cc][n4 << 2];
        *(uint_t*)dl       = pk2(v.x - bf2f(h0), v.y - bf2f(h1));
        *(uint_t*)(dl + 2) = pk2(v.z - bf2f(h2), v.w - bf2f(h3));
    }
    __syncthreads();

    uint4 aq[4], al[4];
    int col = (w << 4) + cl;
    #pragma unroll
    for (int ks = 0; ks < 4; ++ks) {
        ushort_t av[8], lv[8];
        #pragma unroll
        for (int j = 0; j < 8; ++j) {
            av[j] = xs[(ks << 5) + (g << 3) + j][col];
            lv[j] = xl[(ks << 5) + (g << 3) + j][col];
        }
        uint4 a, l;
        a.x = (uint_t)av[0] | ((uint_t)av[1] << 16);
        a.y = (uint_t)av[2] | ((uint_t)av[3] << 16);
        a.z = (uint_t)av[4] | ((uint_t)av[5] << 16);
        a.w = (uint_t)av[6] | ((uint_t)av[7] << 16);
        l.x = (uint_t)lv[0] | ((uint_t)lv[1] << 16);
        l.y = (uint_t)lv[2] | ((uint_t)lv[3] << 16);
        l.z = (uint_t)lv[4] | ((uint_t)lv[5] << 16);
        l.w = (uint_t)lv[6] | ((uint_t)lv[7] << 16);
        aq[ks] = a; al[ks] = l;
    }

    const float* bps[3] = {bf_, bg_, bh_};
    int nb = n0 + (w << 4);

    for (int p = 0; p < 3; ++p) {
        const ushort_t* Wp = Wb + p * 8192;
        float sc = (p == 0) ? LOG2E : 1.0f;    // fold log2e into Q for exp2 softmax
        f32x4 acc[4];
        #pragma unroll
        for (int ot = 0; ot < 4; ++ot) acc[ot] = (f32x4){0.f,0.f,0.f,0.f};
        #pragma unroll
        for (int ks = 0; ks < 4; ++ks) {
            #pragma unroll
            for (int ot = 0; ot < 4; ++ot) {
                uint4 bq = *(const uint4*)(Wp + (((ot << 4) + cl) << 7) + (ks << 5) + (g << 3));
                acc[ot] = MFMA(BC8(aq[ks]), BC8(bq), acc[ot]);
                acc[ot] = MFMA(BC8(al[ks]), BC8(bq), acc[ot]);
            }
        }
        if (p < 2) {
            ushort_t* dst = (p == 0 ? Q : K) + ((size_t)b * NPIX + nb) * CO;
            #pragma unroll
            for (int ot = 0; ot < 4; ++ot) {
                float bias = bps[p][(ot << 4) + cl];
                #pragma unroll
                for (int r = 0; r < 4; ++r)
                    dst[(size_t)((g << 2) + r) * CO + (ot << 4) + cl] = f2bf((acc[ot][r] + bias) * sc);
            }
        } else {
            #pragma unroll
            for (int ot = 0; ot < 4; ++ot) {
                float bias = bps[p][(ot << 4) + cl];
                uint2 pk;
                pk.x = pk2(acc[ot][0] + bias, acc[ot][1] + bias);
                pk.y = pk2(acc[ot][2] + bias, acc[ot][3] + bias);
                ushort_t* Vd = V + (size_t)b * CO * NPIX + (size_t)((ot << 4) + cl) * NPIX + nb + (g << 2);
                *(uint2*)Vd = pk;
            }
        }
    }
}

// ---------------- Kernel 2: flash attention, 16 waves, 3-buffer ring ----------------
// 256 blocks, 1024 thr = 16 waves. qg = w>>2 (16-query group), ks = w&3 (32-key slice).
// Dynamic LDS 118784B:
//   buf[i] @ i*32768 (i=0,1,2): K [128][64] swz ^key&7 (16K) | Vt [64][128] swz ^d&7 (16K)
//   P @98304: per-wave [16q][32k] bf16 pitch 80B (16 x 1280B)
// Ring: iter t computes buf[t%3], issues STAGE(t+2), ends s_waitcnt vmcnt(2) + s_barrier.
// Softmax in log2 domain (Q pre-scaled by log2e) -> raw v_exp_f32.
// Epilogue overlays: mlb/llb @98304 (dead P); Po f32 @0; Pb bf16 @16384.
#define PREG 98304

__global__ __launch_bounds__(1024, 4) void flash_kernel(
    const ushort_t* __restrict__ Q, const ushort_t* __restrict__ K,
    const ushort_t* __restrict__ V, const ushort_t* __restrict__ Wb,
    const float* __restrict__ ba, const float* __restrict__ gamma,
    float* __restrict__ out)
{
    extern __shared__ __align__(16) char smem[];

    int orig = blockIdx.x;
    int bid = ((orig & 7) << 5) | (orig >> 3);      // XCD swizzle: 2 XCDs per batch
    int b = bid >> 6, n0 = (bid & 63) << 6, t = threadIdx.x;
    int w = t >> 6, lane = t & 63, c = lane & 15, g = (lane >> 4) & 3;
    int qg = w >> 2, ks = w & 3;

    const ushort_t* Qb = Q + ((size_t)b * NPIX + n0) * CO;
    const ushort_t* Kb = K + (size_t)b * NPIX * CO;
    const ushort_t* Vb = V + (size_t)b * CO * NPIX;

    // Q fragment: q = 16qg + c, d = 32ds + 8g + j
    uint4 qf[2];
    #pragma unroll
    for (int ds = 0; ds < 2; ++ds)
        qf[ds] = *(const uint4*)(Qb + ((qg << 4) + c) * CO + (ds << 5) + (g << 3));

    f32x4 oac[4];   // O[d][q] partial over 32-key slice: d = 16ds+4g+r, q = 16qg+c
    #pragma unroll
    for (int i = 0; i < 4; ++i) oac[i] = (f32x4){0.f,0.f,0.f,0.f};
    float mreg = -INFINITY, lreg = 0.f;

    char* Pmy = smem + PREG + w * 1280;

    // stage tile kt: 16 waves x 64 lanes x 16B = exactly one 16KB matrix each
    auto STAGE = [&](char* buf, int kt) {
        int cb = w << 6;                             // wave-uniform chunk base
        int ci = cb | lane;                          // 0..1023
        int key = ci >> 3, kc = (ci & 7) ^ (key & 7);
        gload16(Kb + (size_t)((kt << 7) + key) * CO + (kc << 3), buf + (cb << 4));
        int d = ci >> 4, vc = (ci & 15) ^ (d & 7);
        gload16(Vb + (size_t)d * NPIX + (kt << 7) + (vc << 3), buf + 16384 + (cb << 4));
    };

    // prologue: stage tiles 0,1; wait for tile 0 only (tile 1 stays in flight)
    STAGE(smem, 0);
    STAGE(smem + 32768, 1);
    asm volatile("s_waitcnt vmcnt(2)" ::: "memory");
    __builtin_amdgcn_s_barrier();

    int bc = 0;
    for (int kt = 0; kt < 32; ++kt) {
        char* bufc = smem + bc * 32768;
        if (kt < 30) {
            int bn = bc + 2; if (bn >= 3) bn -= 3;
            STAGE(smem + bn * 32768, kt + 2);
        }

        // ---- QK^T: S[key][q] for the wave's 32-key slice ----
        f32x4 sac[2];
        sac[0] = (f32x4){0.f,0.f,0.f,0.f};
        sac[1] = (f32x4){0.f,0.f,0.f,0.f};
        __builtin_amdgcn_s_setprio(1);
        #pragma unroll
        for (int s = 0; s < 2; ++s) {
            int key = (ks << 5) + (s << 4) + c;
            int sw = key & 7;
            uint4 kf0 = *(const uint4*)(bufc + (key << 7) + ((g ^ sw) << 4));
            uint4 kf1 = *(const uint4*)(bufc + (key << 7) + (((4 | g) ^ sw) << 4));
            sac[s] = MFMA(BC8(kf0), BC8(qf[0]), sac[s]);
            sac[s] = MFMA(BC8(kf1), BC8(qf[1]), sac[s]);
        }
        __builtin_amdgcn_s_setprio(0);

        // ---- online softmax, log2 domain, defer-max (THR=11.5 ~ e^8) ----
        float mx = sac[0][0];
        #pragma unroll
        for (int j = 1; j < 4; ++j) mx = fmaxf(mx, sac[0][j]);
        #pragma unroll
        for (int j = 0; j < 4; ++j) mx = fmaxf(mx, sac[1][j]);
        mx = fmaxf(mx, __shfl_xor(mx, 16));
        mx = fmaxf(mx, __shfl_xor(mx, 32));
        if (!__all(mx <= mreg + 11.5f)) {
            float mn = fmaxf(mreg, mx);
            float r  = EXP2(mreg - mn);
            lreg *= r;
            #pragma unroll
            for (int ds = 0; ds < 4; ++ds) oac[ds] *= r;
            mreg = mn;
        }
        float ps[8], ls = 0.f;
        #pragma unroll
        for (int s = 0; s < 2; ++s)
            #pragma unroll
            for (int j = 0; j < 4; ++j) {
                float p = EXP2(sac[s][j] - mreg);
                ps[(s << 2) + j] = p; ls += p;
            }
        ls += __shfl_xor(ls, 16);
        ls += __shfl_xor(ls, 32);
        lreg += ls;
        #pragma unroll
        for (int s = 0; s < 2; ++s) {
            uint2 pk;
            pk.x = cvtpk(ps[(s << 2) + 0], ps[(s << 2) + 1]);
            pk.y = cvtpk(ps[(s << 2) + 2], ps[(s << 2) + 3]);
            *(uint2*)(Pmy + c * 80 + (s << 5) + (g << 3)) = pk;
        }

        // ---- PV over the wave's 32-key slice ----
        uint4 vf[4];
        #pragma unroll
        for (int ds = 0; ds < 4; ++ds) {
            int d = (ds << 4) + c;
            vf[ds] = *(const uint4*)(bufc + 16384 + (d << 8) + ((((ks << 2) | g) ^ (d & 7)) << 4));
        }
        uint4 pf = *(const uint4*)(Pmy + c * 80 + (g << 4));
        __builtin_amdgcn_s_setprio(1);
        #pragma unroll
        for (int ds = 0; ds < 4; ++ds)
            oac[ds] = MFMA(BC8(vf[ds]), BC8(pf), oac[ds]);
        __builtin_amdgcn_s_setprio(0);

        // counted wait: t+1's loads landed, t+2's stay in flight across the barrier
        if (kt < 30) asm volatile("s_waitcnt vmcnt(2)" ::: "memory");
        else         asm volatile("s_waitcnt vmcnt(0)" ::: "memory");
        __builtin_amdgcn_s_barrier();
        if (++bc == 3) bc = 0;
    }

    // ---- stats exchange: mlb/llb [16 waves][16 q] ----
    float* mlb = (float*)(smem + PREG);
    float* llb = (float*)(smem + PREG + 1024);
    if (lane < 16) {
        mlb[(w << 4) + lane] = mreg;
        llb[(w << 4) + lane] = lreg;
    }
    __syncthreads();

    int base = qg << 2;
    float m0 = mlb[((base + 0) << 4) + c], m1 = mlb[((base + 1) << 4) + c];
    float m2 = mlb[((base + 2) << 4) + c], m3 = mlb[((base + 3) << 4) + c];
    float M  = fmaxf(fmaxf(m0, m1), fmaxf(m2, m3));
    float a0 = EXP2(m0 - M), a1 = EXP2(m1 - M), a2 = EXP2(m2 - M), a3 = EXP2(m3 - M);
    float L  = a0 * llb[((base + 0) << 4) + c] + a1 * llb[((base + 1) << 4) + c]
             + a2 * llb[((base + 2) << 4) + c] + a3 * llb[((base + 3) << 4) + c];
    float aw = (ks == 0) ? a0 : (ks == 1) ? a1 : (ks == 2) ? a2 : a3;
    float fac = aw / L;
    #pragma unroll
    for (int ds = 0; ds < 4; ++ds) oac[ds] *= fac;

    // ---- accumulate scaled partials into Po f32 @0 (dead buf0 K), rounds ks = 0,1,2 ----
    for (int r = 0; r < 3; ++r) {
        if (ks == r) {
            #pragma unroll
            for (int ds = 0; ds < 4; ++ds) {
                int q = (qg << 4) + c;
                int off = (q << 8) + ((((ds << 2) | g) ^ (q & 7)) << 4);
                f32x4 v = oac[ds];
                if (r > 0) v += *(const f32x4*)(smem + off);
                *(f32x4*)(smem + off) = v;
            }
        }
        __syncthreads();
    }
    // round 3: final add -> bf16 Pb @16384 ([64q][72] ushort, pitch 144B)
    ushort_t* Pb = (ushort_t*)(smem + 16384);
    if (ks == 3) {
        #pragma unroll
        for (int ds = 0; ds < 4; ++ds) {
            int q = (qg << 4) + c;
            int off = (q << 8) + ((((ds << 2) | g) ^ (q & 7)) << 4);
            f32x4 v = oac[ds] + *(const f32x4*)(smem + off);
            uint2 pk;
            pk.x = pk2(v[0], v[1]);
            pk.y = pk2(v[2], v[3]);
            *(uint2*)(Pb + q * 72 + (ds << 4) + (g << 2)) = pk;
        }
    }
    __syncthreads();

    // ---- fused outconv: out[o][q] = gamma*(Wa[o][:] . Pb[q][:] + ba[o]) ----
    const ushort_t* Wab = Wb + 24576;
    float gm = gamma[0];
    int ot = w >> 2, qt = w & 3;
    f32x4 acc2 = (f32x4){0.f,0.f,0.f,0.f};
    #pragma unroll
    for (int k2 = 0; k2 < 2; ++k2) {
        uint4 af  = *(const uint4*)(Wab + (((ot << 4) + c) << 6) + (k2 << 5) + (g << 3));
        uint4 pfq = *(const uint4*)((char*)Pb + (((qt << 4) + c)) * 144 + (k2 << 6) + (g << 4));
        acc2 = MFMA(BC8(af), BC8(pfq), acc2);
    }
    float* ob = out + (size_t)b * CO * NPIX + n0;
    #pragma unroll
    for (int r = 0; r < 4; ++r) {
        int o = (ot << 4) + (g << 2) + r;
        ob[(size_t)o * NPIX + (qt << 4) + c] = gm * (acc2[r] + ba[o]);
    }
}

extern "C" void kernel_launch(void* const* d_in, const int* in_sizes, int n_in,
                              void* d_out, int out_size, void* d_ws, size_t ws_size,
                              hipStream_t stream) {
    const float* x     = (const float*)d_in[0];
    const float* Wf    = (const float*)d_in[1];
    const float* bf_   = (const float*)d_in[2];
    const float* Wg    = (const float*)d_in[3];
    const float* bg_   = (const float*)d_in[4];
    const float* Wh    = (const float*)d_in[5];
    const float* bh_   = (const float*)d_in[6];
    const float* Wa    = (const float*)d_in[7];
    const float* ba    = (const float*)d_in[8];
    const float* gamma = (const float*)d_in[9];
    float* out = (float*)d_out;

    ushort_t* Wb = (ushort_t*)d_ws;                               // 57344 B
    const size_t matb = (size_t)BATCH * NPIX * CO;                // 1M elems
    ushort_t* Q = (ushort_t*)((char*)d_ws + 65536);               // 2 MB
    ushort_t* K = Q + matb;                                       // 2 MB
    ushort_t* V = K + matb;                                       // 2 MB (transposed [B][64][N])

    wconv_kernel<<<16, 256, 0, stream>>>(Wf, Wg, Wh, Wa, Wb);
    proj_kernel<<<BATCH * (NPIX / 64), 256, 0, stream>>>(x, Wb, bf_, bg_, bh_, Q, K, V);
    flash_kernel<<<BATCH * (NPIX / 64), 1024, 118784, stream>>>(Q, K, V, Wb, ba, gamma, out);
}

// Round 10
// 64.128 us; speedup vs baseline: 1.2590x; 1.1414x over previous
//
#include <hip/hip_runtime.h>
#include <math.h>

#define BATCH 4
#define CIN   128
#define CO    64
#define NPIX  4096
#define LOG2E 1.4426950408889634f

typedef unsigned int   uint_t;
typedef unsigned short ushort_t;
typedef __bf16 bfx8 __attribute__((ext_vector_type(8)));
typedef float  f32x4 __attribute__((ext_vector_type(4)));

#define MFMA(a,b,c) __builtin_amdgcn_mfma_f32_16x16x32_bf16((a),(b),(c),0,0,0)
#define BC8(x) __builtin_bit_cast(bfx8,(x))

#if __has_builtin(__builtin_amdgcn_exp2f)
#define EXP2(x) __builtin_amdgcn_exp2f(x)
#else
#define EXP2(x) exp2f(x)
#endif

static __device__ __forceinline__ ushort_t f2bf(float f) {
    uint_t u = __builtin_bit_cast(uint_t, f);
    u = (u + 0x7fffu + ((u >> 16) & 1u)) >> 16;   // RNE
    return (ushort_t)u;
}
static __device__ __forceinline__ float bf2f(ushort_t h) {
    return __builtin_bit_cast(float, (uint_t)h << 16);
}
static __device__ __forceinline__ uint_t pk2(float a, float b) {
    return (uint_t)f2bf(a) | ((uint_t)f2bf(b) << 16);
}
static __device__ __forceinline__ uint_t cvtpk(float lo, float hi) {
    uint_t r;
    asm("v_cvt_pk_bf16_f32 %0, %1, %2" : "=v"(r) : "v"(lo), "v"(hi));
    return r;
}
static __device__ __forceinline__ void gload16(const void* g, void* l) {
    __builtin_amdgcn_global_load_lds(
        (const __attribute__((address_space(1))) void*)g,
        (__attribute__((address_space(3))) void*)l, 16, 0, 0);
}

// ---------------- Kernel 0: convert Wf,Wg,Wh,Wa to bf16 in ws ----------------
__global__ __launch_bounds__(256) void wconv_kernel(
    const float* __restrict__ Wf, const float* __restrict__ Wg,
    const float* __restrict__ Wh, const float* __restrict__ Wa,
    ushort_t* __restrict__ Wb)
{
    int gid = blockIdx.x * 256 + threadIdx.x;
    for (int e = gid; e < 28672; e += 4096) {
        float v;
        if      (e < 8192)  v = Wf[e];
        else if (e < 16384) v = Wg[e - 8192];
        else if (e < 24576) v = Wh[e - 16384];
        else                v = Wa[e - 24576];
        Wb[e] = f2bf(v);
    }
}

// ---------------- Kernel 1: MFMA projections, LDS-free ----------------
// A-fragments load directly from global x (same values as the R4-verified LDS path:
// x[b][k][n0+16w+c]). x split hi/lo bf16. V stored sigma-PERMUTED: within each block
// of 8 columns, odd blocks swap their 4-col halves (gi = g ^ ((g>>1)&1)) so flash's
// PV B-fragment (register P from permuted QK^T) matches V's element order.
__global__ __launch_bounds__(256) void proj_kernel(
    const float* __restrict__ x, const ushort_t* __restrict__ Wb,
    const float* __restrict__ bf_, const float* __restrict__ bg_, const float* __restrict__ bh_,
    ushort_t* __restrict__ Q, ushort_t* __restrict__ K, ushort_t* __restrict__ V)
{
    int bid = blockIdx.x, b = bid >> 6, n0 = (bid & 63) << 6, t = threadIdx.x;
    int w = t >> 6, lane = t & 63, cl = lane & 15, g = (lane >> 4) & 3;

    const float* xcol = x + (size_t)b * CIN * NPIX + n0 + (w << 4) + cl;

    uint4 aq[4], al[4];
    #pragma unroll
    for (int ks = 0; ks < 4; ++ks) {
        float v[8];
        #pragma unroll
        for (int j = 0; j < 8; ++j)
            v[j] = xcol[(size_t)((ks << 5) + (g << 3) + j) * NPIX];
        ushort_t hv[8];
        #pragma unroll
        for (int j = 0; j < 8; ++j) hv[j] = f2bf(v[j]);
        uint4 a, l;
        a.x = (uint_t)hv[0] | ((uint_t)hv[1] << 16);
        a.y = (uint_t)hv[2] | ((uint_t)hv[3] << 16);
        a.z = (uint_t)hv[4] | ((uint_t)hv[5] << 16);
        a.w = (uint_t)hv[6] | ((uint_t)hv[7] << 16);
        l.x = pk2(v[0] - bf2f(hv[0]), v[1] - bf2f(hv[1]));
        l.y = pk2(v[2] - bf2f(hv[2]), v[3] - bf2f(hv[3]));
        l.z = pk2(v[4] - bf2f(hv[4]), v[5] - bf2f(hv[5]));
        l.w = pk2(v[6] - bf2f(hv[6]), v[7] - bf2f(hv[7]));
        aq[ks] = a; al[ks] = l;
    }

    const float* bps[3] = {bf_, bg_, bh_};
    int nb = n0 + (w << 4);

    for (int p = 0; p < 3; ++p) {
        const ushort_t* Wp = Wb + p * 8192;
        float sc = (p == 0) ? LOG2E : 1.0f;    // fold log2e into Q for exp2 softmax
        f32x4 acc[4];
        #pragma unroll
        for (int ot = 0; ot < 4; ++ot) acc[ot] = (f32x4){0.f,0.f,0.f,0.f};
        #pragma unroll
        for (int ks = 0; ks < 4; ++ks) {
            #pragma unroll
            for (int ot = 0; ot < 4; ++ot) {
                uint4 bq = *(const uint4*)(Wp + (((ot << 4) + cl) << 7) + (ks << 5) + (g << 3));
                acc[ot] = MFMA(BC8(aq[ks]), BC8(bq), acc[ot]);
                acc[ot] = MFMA(BC8(al[ks]), BC8(bq), acc[ot]);
            }
        }
        if (p < 2) {
            ushort_t* dst = (p == 0 ? Q : K) + ((size_t)b * NPIX + nb) * CO;
            #pragma unroll
            for (int ot = 0; ot < 4; ++ot) {
                float bias = bps[p][(ot << 4) + cl];
                #pragma unroll
                for (int r = 0; r < 4; ++r)
                    dst[(size_t)((g << 2) + r) * CO + (ot << 4) + cl] = f2bf((acc[ot][r] + bias) * sc);
            }
        } else {
            int gi = g ^ ((g >> 1) & 1);       // sigma: odd 8-col blocks swap 4-col halves
            #pragma unroll
            for (int ot = 0; ot < 4; ++ot) {
                float bias = bps[p][(ot << 4) + cl];
                uint2 pk;
                pk.x = pk2(acc[ot][0] + bias, acc[ot][1] + bias);
                pk.y = pk2(acc[ot][2] + bias, acc[ot][3] + bias);
                ushort_t* Vd = V + (size_t)b * CO * NPIX + (size_t)((ot << 4) + cl) * NPIX + nb + (gi << 2);
                *(uint2*)Vd = pk;
            }
        }
    }
}

// ---------------- Kernel 2: flash attention, register-resident P ----------------
// 256 blocks, 1024 thr = 16 waves = 4 q-groups (qg, 16q) x 4 key-slices (ks, 32 keys).
// QK^T uses PERMUTED key->row mapping kappa(m,4g+r) = 8g + 4*((g&1)^m) + r so that
// lane (c,g) holds P for keys {8g..8g+7} == the 16x16x32 B-fragment layout (k=8g+j).
// V's sigma store order makes A/B element orders match for all g. P never touches LDS.
// Dynamic LDS 100352B:
//   buf[i] @ i*32768 (i=0,1,2): K [128][64] swz ^key&7 (16K) | Vt [64][128] swz ^d&7 (16K)
//   stats @98304: mlb (1KB) + llb (1KB)
// Ring: iter t computes buf[t%3], issues STAGE(t+2), ends s_waitcnt vmcnt(2) + s_barrier.
// Epilogue overlays: Po f32 @0; Pb bf16 @16384.
#define PREG 98304

__global__ __launch_bounds__(1024, 4) void flash_kernel(
    const ushort_t* __restrict__ Q, const ushort_t* __restrict__ K,
    const ushort_t* __restrict__ V, const ushort_t* __restrict__ Wb,
    const float* __restrict__ ba, const float* __restrict__ gamma,
    float* __restrict__ out)
{
    extern __shared__ __align__(16) char smem[];

    int orig = blockIdx.x;
    int bid = ((orig & 7) << 5) | (orig >> 3);      // XCD swizzle: 2 XCDs per batch
    int b = bid >> 6, n0 = (bid & 63) << 6, t = threadIdx.x;
    int w = t >> 6, lane = t & 63, c = lane & 15, g = (lane >> 4) & 3;
    int qg = w >> 2, ks = w & 3;

    const ushort_t* Qb = Q + ((size_t)b * NPIX + n0) * CO;
    const ushort_t* Kb = K + (size_t)b * NPIX * CO;
    const ushort_t* Vb = V + (size_t)b * CO * NPIX;

    // Q fragment: q = 16qg + c, d = 32ds + 8g + j
    uint4 qf[2];
    #pragma unroll
    for (int ds = 0; ds < 2; ++ds)
        qf[ds] = *(const uint4*)(Qb + ((qg << 4) + c) * CO + (ds << 5) + (g << 3));

    f32x4 oac[4];   // O[d][q] partial over 32-key slice: d = 16dt+4g+r, q = 16qg+c
    #pragma unroll
    for (int i = 0; i < 4; ++i) oac[i] = (f32x4){0.f,0.f,0.f,0.f};
    float mreg = -INFINITY, lreg = 0.f;

    // kappa-permuted K fragment offsets (A row c holds key kappa(m,c) of this slice)
    int cg = c >> 2;
    int keyA = (ks << 5) + (cg << 3) + ((cg & 1) << 2) + (c & 3);
    int keyB = keyA ^ 4;
    int swA  = ((cg & 1) << 2) + (c & 3);
    int swB  = swA ^ 4;
    int kA0off = (keyA << 7) + (((g     ) ^ swA) << 4);
    int kA1off = (keyA << 7) + (((4 | g) ^ swA) << 4);
    int kB0off = (keyB << 7) + (((g     ) ^ swB) << 4);
    int kB1off = (keyB << 7) + (((4 | g) ^ swB) << 4);
    int vfoff[4];
    #pragma unroll
    for (int dt = 0; dt < 4; ++dt) {
        int d = (dt << 4) + c;
        vfoff[dt] = 16384 + (d << 8) + ((((ks << 2) | g) ^ (d & 7)) << 4);
    }

    // stage tile kt: 16 waves x 64 lanes x 16B = one 16KB matrix each (K and Vt)
    auto STAGE = [&](char* buf, int kt) {
        int cb = w << 6;                             // wave-uniform chunk base
        int ci = cb | lane;                          // 0..1023
        int key = ci >> 3, kc = (ci & 7) ^ (key & 7);
        gload16(Kb + (size_t)((kt << 7) + key) * CO + (kc << 3), buf + (cb << 4));
        int d = ci >> 4, vc = (ci & 15) ^ (d & 7);
        gload16(Vb + (size_t)d * NPIX + (kt << 7) + (vc << 3), buf + 16384 + (cb << 4));
    };

    // prologue: stage tiles 0,1; wait for tile 0 only (tile 1 stays in flight)
    STAGE(smem, 0);
    STAGE(smem + 32768, 1);
    asm volatile("s_waitcnt vmcnt(2)" ::: "memory");
    __builtin_amdgcn_s_barrier();

    int bc = 0;
    for (int kt = 0; kt < 32; ++kt) {
        char* bufc = smem + bc * 32768;
        if (kt < 30) {
            int bn = bc + 2; if (bn >= 3) bn -= 3;
            STAGE(smem + bn * 32768, kt + 2);
        }

        // ---- QK^T with permuted rows: sac0[r] = S[8g+4(g&1)+r], sac1[r] = S[8g+4(1-(g&1))+r] ----
        uint4 kA0 = *(const uint4*)(bufc + kA0off);
        uint4 kA1 = *(const uint4*)(bufc + kA1off);
        uint4 kB0 = *(const uint4*)(bufc + kB0off);
        uint4 kB1 = *(const uint4*)(bufc + kB1off);
        f32x4 sac0 = (f32x4){0.f,0.f,0.f,0.f};
        f32x4 sac1 = (f32x4){0.f,0.f,0.f,0.f};
        __builtin_amdgcn_s_setprio(1);
        sac0 = MFMA(BC8(kA0), BC8(qf[0]), sac0);
        sac0 = MFMA(BC8(kA1), BC8(qf[1]), sac0);
        sac1 = MFMA(BC8(kB0), BC8(qf[0]), sac1);
        sac1 = MFMA(BC8(kB1), BC8(qf[1]), sac1);
        __builtin_amdgcn_s_setprio(0);

        // ---- online softmax, log2 domain, defer-max ----
        float mx = fmaxf(fmaxf(fmaxf(sac0[0], sac0[1]), fmaxf(sac0[2], sac0[3])),
                         fmaxf(fmaxf(sac1[0], sac1[1]), fmaxf(sac1[2], sac1[3])));
        mx = fmaxf(mx, __shfl_xor(mx, 16));
        mx = fmaxf(mx, __shfl_xor(mx, 32));
        if (!__all(mx <= mreg + 11.5f)) {
            float mn = fmaxf(mreg, mx);
            float r  = EXP2(mreg - mn);
            lreg *= r;
            #pragma unroll
            for (int dt = 0; dt < 4; ++dt) oac[dt] *= r;
            mreg = mn;
        }
        float p0 = EXP2(sac0[0] - mreg), p1 = EXP2(sac0[1] - mreg);
        float p2 = EXP2(sac0[2] - mreg), p3 = EXP2(sac0[3] - mreg);
        float p4 = EXP2(sac1[0] - mreg), p5 = EXP2(sac1[1] - mreg);
        float p6 = EXP2(sac1[2] - mreg), p7 = EXP2(sac1[3] - mreg);
        float ls = ((p0 + p1) + (p2 + p3)) + ((p4 + p5) + (p6 + p7));
        ls += __shfl_xor(ls, 16);
        ls += __shfl_xor(ls, 32);
        lreg += ls;
        uint4 pb;
        pb.x = cvtpk(p0, p1);
        pb.y = cvtpk(p2, p3);
        pb.z = cvtpk(p4, p5);
        pb.w = cvtpk(p6, p7);

        // ---- PV: register P as B-fragment; V element order matches via sigma store ----
        uint4 vf0 = *(const uint4*)(bufc + vfoff[0]);
        uint4 vf1 = *(const uint4*)(bufc + vfoff[1]);
        uint4 vf2 = *(const uint4*)(bufc + vfoff[2]);
        uint4 vf3 = *(const uint4*)(bufc + vfoff[3]);
        __builtin_amdgcn_s_setprio(1);
        oac[0] = MFMA(BC8(vf0), BC8(pb), oac[0]);
        oac[1] = MFMA(BC8(vf1), BC8(pb), oac[1]);
        oac[2] = MFMA(BC8(vf2), BC8(pb), oac[2]);
        oac[3] = MFMA(BC8(vf3), BC8(pb), oac[3]);
        __builtin_amdgcn_s_setprio(0);

        // counted wait: t+1's loads landed, t+2's stay in flight across the barrier
        if (kt < 30) asm volatile("s_waitcnt vmcnt(2)" ::: "memory");
        else         asm volatile("s_waitcnt vmcnt(0)" ::: "memory");
        __builtin_amdgcn_s_barrier();
        if (++bc == 3) bc = 0;
    }

    // ---- stats exchange: mlb/llb [16 waves][16 q] ----
    float* mlb = (float*)(smem + PREG);
    float* llb = (float*)(smem + PREG + 1024);
    if (lane < 16) {
        mlb[(w << 4) + lane] = mreg;
        llb[(w << 4) + lane] = lreg;
    }
    __syncthreads();

    int base = qg << 2;
    float m0 = mlb[((base + 0) << 4) + c], m1 = mlb[((base + 1) << 4) + c];
    float m2 = mlb[((base + 2) << 4) + c], m3 = mlb[((base + 3) << 4) + c];
    float M  = fmaxf(fmaxf(m0, m1), fmaxf(m2, m3));
    float a0 = EXP2(m0 - M), a1 = EXP2(m1 - M), a2 = EXP2(m2 - M), a3 = EXP2(m3 - M);
    float L  = a0 * llb[((base + 0) << 4) + c] + a1 * llb[((base + 1) << 4) + c]
             + a2 * llb[((base + 2) << 4) + c] + a3 * llb[((base + 3) << 4) + c];
    float aw = (ks == 0) ? a0 : (ks == 1) ? a1 : (ks == 2) ? a2 : a3;
    float fac = aw / L;
    #pragma unroll
    for (int dt = 0; dt < 4; ++dt) oac[dt] *= fac;

    // ---- accumulate scaled partials into Po f32 @0, rounds ks = 0,1,2 ----
    for (int r = 0; r < 3; ++r) {
        if (ks == r) {
            #pragma unroll
            for (int dt = 0; dt < 4; ++dt) {
                int q = (qg << 4) + c;
                int off = (q << 8) + ((((dt << 2) | g) ^ (q & 7)) << 4);
                f32x4 v = oac[dt];
                if (r > 0) v += *(const f32x4*)(smem + off);
                *(f32x4*)(smem + off) = v;
            }
        }
        __syncthreads();
    }
    // round 3: final add -> bf16 Pb @16384 ([64q][72] ushort, pitch 144B)
    ushort_t* Pb = (ushort_t*)(smem + 16384);
    if (ks == 3) {
        #pragma unroll
        for (int dt = 0; dt < 4; ++dt) {
            int q = (qg << 4) + c;
            int off = (q << 8) + ((((dt << 2) | g) ^ (q & 7)) << 4);
            f32x4 v = oac[dt] + *(const f32x4*)(smem + off);
            uint2 pk;
            pk.x = pk2(v[0], v[1]);
            pk.y = pk2(v[2], v[3]);
            *(uint2*)(Pb + q * 72 + (dt << 4) + (g << 2)) = pk;
        }
    }
    __syncthreads();

    // ---- fused outconv: out[o][q] = gamma*(Wa[o][:] . Pb[q][:] + ba[o]) ----
    const ushort_t* Wab = Wb + 24576;
    float gm = gamma[0];
    int ot = w >> 2, qt3 = w & 3;
    f32x4 acc2 = (f32x4){0.f,0.f,0.f,0.f};
    #pragma unroll
    for (int k2 = 0; k2 < 2; ++k2) {
        uint4 af  = *(const uint4*)(Wab + (((ot << 4) + c) << 6) + (k2 << 5) + (g << 3));
        uint4 pfq = *(const uint4*)((char*)Pb + (((qt3 << 4) + c)) * 144 + (k2 << 6) + (g << 4));
        acc2 = MFMA(BC8(af), BC8(pfq), acc2);
    }
    float* ob = out + (size_t)b * CO * NPIX + n0;
    #pragma unroll
    for (int r = 0; r < 4; ++r) {
        int o = (ot << 4) + (g << 2) + r;
        ob[(size_t)o * NPIX + (qt3 << 4) + c] = gm * (acc2[r] + ba[o]);
    }
}

extern "C" void kernel_launch(void* const* d_in, const int* in_sizes, int n_in,
                              void* d_out, int out_size, void* d_ws, size_t ws_size,
                              hipStream_t stream) {
    const float* x     = (const float*)d_in[0];
    const float* Wf    = (const float*)d_in[1];
    const float* bf_   = (const float*)d_in[2];
    const float* Wg    = (const float*)d_in[3];
    const float* bg_   = (const float*)d_in[4];
    const float* Wh    = (const float*)d_in[5];
    const float* bh_   = (const float*)d_in[6];
    const float* Wa    = (const float*)d_in[7];
    const float* ba    = (const float*)d_in[8];
    const float* gamma = (const float*)d_in[9];
    float* out = (float*)d_out;

    ushort_t* Wb = (ushort_t*)d_ws;                               // 57344 B
    const size_t matb = (size_t)BATCH * NPIX * CO;                // 1M elems
    ushort_t* Q = (ushort_t*)((char*)d_ws + 65536);               // 2 MB
    ushort_t* K = Q + matb;                                       // 2 MB
    ushort_t* V = K + matb;                                       // 2 MB (transposed [B][64][N], sigma-permuted cols)

    wconv_kernel<<<16, 256, 0, stream>>>(Wf, Wg, Wh, Wa, Wb);
    proj_kernel<<<BATCH * (NPIX / 64), 256, 0, stream>>>(x, Wb, bf_, bg_, bh_, Q, K, V);
    flash_kernel<<<BATCH * (NPIX / 64), 1024, 100352, stream>>>(Q, K, V, Wb, ba, gamma, out);
}

// Round 12
// 58.074 us; speedup vs baseline: 1.3902x; 1.1042x over previous
//
#include <hip/hip_runtime.h>
#include <math.h>

#define BATCH 4
#define CIN   128
#define CO    64
#define NPIX  4096
#define LOG2E 1.4426950408889634f

typedef unsigned int   uint_t;
typedef unsigned short ushort_t;
typedef __bf16 bfx8 __attribute__((ext_vector_type(8)));
typedef float  f32x4 __attribute__((ext_vector_type(4)));

#define MFMA(a,b,c) __builtin_amdgcn_mfma_f32_16x16x32_bf16((a),(b),(c),0,0,0)
#define BC8(x) __builtin_bit_cast(bfx8,(x))

#if __has_builtin(__builtin_amdgcn_exp2f)
#define EXP2(x) __builtin_amdgcn_exp2f(x)
#else
#define EXP2(x) exp2f(x)
#endif

static __device__ __forceinline__ ushort_t f2bf(float f) {
    uint_t u = __builtin_bit_cast(uint_t, f);
    u = (u + 0x7fffu + ((u >> 16) & 1u)) >> 16;   // RNE
    return (ushort_t)u;
}
static __device__ __forceinline__ float bf2f(ushort_t h) {
    return __builtin_bit_cast(float, (uint_t)h << 16);
}
static __device__ __forceinline__ uint_t pk2(float a, float b) {
    return (uint_t)f2bf(a) | ((uint_t)f2bf(b) << 16);
}
static __device__ __forceinline__ uint_t cvtpk(float lo, float hi) {
    uint_t r;
    asm("v_cvt_pk_bf16_f32 %0, %1, %2" : "=v"(r) : "v"(lo), "v"(hi));
    return r;
}
static __device__ __forceinline__ void gload16(const void* g, void* l) {
    __builtin_amdgcn_global_load_lds(
        (const __attribute__((address_space(1))) void*)g,
        (__attribute__((address_space(3))) void*)l, 16, 0, 0);
}

// ---------------- Kernel 0: convert Wf,Wg,Wh,Wa to bf16 in ws ----------------
__global__ __launch_bounds__(256) void wconv_kernel(
    const float* __restrict__ Wf, const float* __restrict__ Wg,
    const float* __restrict__ Wh, const float* __restrict__ Wa,
    ushort_t* __restrict__ Wb)
{
    int gid = blockIdx.x * 256 + threadIdx.x;
    for (int e = gid; e < 28672; e += 4096) {
        float v;
        if      (e < 8192)  v = Wf[e];
        else if (e < 16384) v = Wg[e - 8192];
        else if (e < 24576) v = Wh[e - 16384];
        else                v = Wa[e - 24576];
        Wb[e] = f2bf(v);
    }
}

// ---------------- Kernel 1: MFMA projections, LDS-free (verified R10) ----------------
__global__ __launch_bounds__(256) void proj_kernel(
    const float* __restrict__ x, const ushort_t* __restrict__ Wb,
    const float* __restrict__ bf_, const float* __restrict__ bg_, const float* __restrict__ bh_,
    ushort_t* __restrict__ Q, ushort_t* __restrict__ K, ushort_t* __restrict__ V)
{
    int bid = blockIdx.x, b = bid >> 6, n0 = (bid & 63) << 6, t = threadIdx.x;
    int w = t >> 6, lane = t & 63, cl = lane & 15, g = (lane >> 4) & 3;

    const float* xcol = x + (size_t)b * CIN * NPIX + n0 + (w << 4) + cl;

    uint4 aq[4], al[4];
    #pragma unroll
    for (int ks = 0; ks < 4; ++ks) {
        float v[8];
        #pragma unroll
        for (int j = 0; j < 8; ++j)
            v[j] = xcol[(size_t)((ks << 5) + (g << 3) + j) * NPIX];
        ushort_t hv[8];
        #pragma unroll
        for (int j = 0; j < 8; ++j) hv[j] = f2bf(v[j]);
        uint4 a, l;
        a.x = (uint_t)hv[0] | ((uint_t)hv[1] << 16);
        a.y = (uint_t)hv[2] | ((uint_t)hv[3] << 16);
        a.z = (uint_t)hv[4] | ((uint_t)hv[5] << 16);
        a.w = (uint_t)hv[6] | ((uint_t)hv[7] << 16);
        l.x = pk2(v[0] - bf2f(hv[0]), v[1] - bf2f(hv[1]));
        l.y = pk2(v[2] - bf2f(hv[2]), v[3] - bf2f(hv[3]));
        l.z = pk2(v[4] - bf2f(hv[4]), v[5] - bf2f(hv[5]));
        l.w = pk2(v[6] - bf2f(hv[6]), v[7] - bf2f(hv[7]));
        aq[ks] = a; al[ks] = l;
    }

    const float* bps[3] = {bf_, bg_, bh_};
    int nb = n0 + (w << 4);

    for (int p = 0; p < 3; ++p) {
        const ushort_t* Wp = Wb + p * 8192;
        float sc = (p == 0) ? LOG2E : 1.0f;    // fold log2e into Q for exp2 softmax
        f32x4 acc[4];
        #pragma unroll
        for (int ot = 0; ot < 4; ++ot) acc[ot] = (f32x4){0.f,0.f,0.f,0.f};
        #pragma unroll
        for (int ks = 0; ks < 4; ++ks) {
            #pragma unroll
            for (int ot = 0; ot < 4; ++ot) {
                uint4 bq = *(const uint4*)(Wp + (((ot << 4) + cl) << 7) + (ks << 5) + (g << 3));
                acc[ot] = MFMA(BC8(aq[ks]), BC8(bq), acc[ot]);
                acc[ot] = MFMA(BC8(al[ks]), BC8(bq), acc[ot]);
            }
        }
        if (p < 2) {
            ushort_t* dst = (p == 0 ? Q : K) + ((size_t)b * NPIX + nb) * CO;
            #pragma unroll
            for (int ot = 0; ot < 4; ++ot) {
                float bias = bps[p][(ot << 4) + cl];
                #pragma unroll
                for (int r = 0; r < 4; ++r)
                    dst[(size_t)((g << 2) + r) * CO + (ot << 4) + cl] = f2bf((acc[ot][r] + bias) * sc);
            }
        } else {
            int gi = g ^ ((g >> 1) & 1);       // sigma: odd 8-col blocks swap 4-col halves
            #pragma unroll
            for (int ot = 0; ot < 4; ++ot) {
                float bias = bps[p][(ot << 4) + cl];
                uint2 pk;
                pk.x = pk2(acc[ot][0] + bias, acc[ot][1] + bias);
                pk.y = pk2(acc[ot][2] + bias, acc[ot][3] + bias);
                ushort_t* Vd = V + (size_t)b * CO * NPIX + (size_t)((ot << 4) + cl) * NPIX + nb + (gi << 2);
                *(uint2*)Vd = pk;
            }
        }
    }
}

// ---------------- Kernel 2: flash attention, register-P, 2 tiles per barrier ----------------
// 256 blocks, 1024 thr = 16 waves = 4 q-groups (qg) x 4 key-slices (ks, 32 keys).
// Per-tile dataflow is byte-identical to verified R10 (kappa-permuted QK^T rows +
// sigma-permuted V store keep P in registers). Phase i: STAGE tiles 2i+2,2i+3 into the
// buffer pair read at phase i-1 (barrier-protected), compute tiles 2i,2i+1, one barrier.
// Dynamic LDS 133120B: buf[j] @ j*32768 (j=0..3, 4-ring); stats @131072.
// Epilogue overlays: Po f32 @0; Pb bf16 @16384.
#define PREG 131072

__global__ __launch_bounds__(1024, 4) void flash_kernel(
    const ushort_t* __restrict__ Q, const ushort_t* __restrict__ K,
    const ushort_t* __restrict__ V, const ushort_t* __restrict__ Wb,
    const float* __restrict__ ba, const float* __restrict__ gamma,
    float* __restrict__ out)
{
    extern __shared__ __align__(16) char smem[];

    int orig = blockIdx.x;
    int bid = ((orig & 7) << 5) | (orig >> 3);      // XCD swizzle: 2 XCDs per batch
    int b = bid >> 6, n0 = (bid & 63) << 6, t = threadIdx.x;
    int w = t >> 6, lane = t & 63, c = lane & 15, g = (lane >> 4) & 3;
    int qg = w >> 2, ks = w & 3;

    const ushort_t* Qb = Q + ((size_t)b * NPIX + n0) * CO;
    const ushort_t* Kb = K + (size_t)b * NPIX * CO;
    const ushort_t* Vb = V + (size_t)b * CO * NPIX;

    // Q fragment: q = 16qg + c, d = 32ds + 8g + j
    uint4 qf[2];
    #pragma unroll
    for (int ds = 0; ds < 2; ++ds)
        qf[ds] = *(const uint4*)(Qb + ((qg << 4) + c) * CO + (ds << 5) + (g << 3));

    f32x4 oac[4];
    #pragma unroll
    for (int i = 0; i < 4; ++i) oac[i] = (f32x4){0.f,0.f,0.f,0.f};
    float mreg = -INFINITY, lreg = 0.f;

    // kappa-permuted K fragment offsets (verified R10)
    int cg = c >> 2;
    int keyA = (ks << 5) + (cg << 3) + ((cg & 1) << 2) + (c & 3);
    int keyB = keyA ^ 4;
    int swA  = ((cg & 1) << 2) + (c & 3);
    int swB  = swA ^ 4;
    int kA0off = (keyA << 7) + (((g     ) ^ swA) << 4);
    int kA1off = (keyA << 7) + (((4 | g) ^ swA) << 4);
    int kB0off = (keyB << 7) + (((g     ) ^ swB) << 4);
    int kB1off = (keyB << 7) + (((4 | g) ^ swB) << 4);
    int vfoff[4];
    #pragma unroll
    for (int dt = 0; dt < 4; ++dt) {
        int d = (dt << 4) + c;
        vfoff[dt] = 16384 + (d << 8) + ((((ks << 2) | g) ^ (d & 7)) << 4);
    }

    auto STAGE = [&](char* buf, int kt) {
        int cb = w << 6;
        int ci = cb | lane;
        int key = ci >> 3, kc = (ci & 7) ^ (key & 7);
        gload16(Kb + (size_t)((kt << 7) + key) * CO + (kc << 3), buf + (cb << 4));
        int d = ci >> 4, vc = (ci & 15) ^ (d & 7);
        gload16(Vb + (size_t)d * NPIX + (kt << 7) + (vc << 3), buf + 16384 + (cb << 4));
    };

    // exactly R10's per-tile body: QK^T -> in-register softmax -> PV
    auto DOTILE = [&](char* bufc) {
        uint4 kA0 = *(const uint4*)(bufc + kA0off);
        uint4 kA1 = *(const uint4*)(bufc + kA1off);
        uint4 kB0 = *(const uint4*)(bufc + kB0off);
        uint4 kB1 = *(const uint4*)(bufc + kB1off);
        f32x4 sac0 = (f32x4){0.f,0.f,0.f,0.f};
        f32x4 sac1 = (f32x4){0.f,0.f,0.f,0.f};
        __builtin_amdgcn_s_setprio(1);
        sac0 = MFMA(BC8(kA0), BC8(qf[0]), sac0);
        sac0 = MFMA(BC8(kA1), BC8(qf[1]), sac0);
        sac1 = MFMA(BC8(kB0), BC8(qf[0]), sac1);
        sac1 = MFMA(BC8(kB1), BC8(qf[1]), sac1);
        __builtin_amdgcn_s_setprio(0);

        float mx = fmaxf(fmaxf(fmaxf(sac0[0], sac0[1]), fmaxf(sac0[2], sac0[3])),
                         fmaxf(fmaxf(sac1[0], sac1[1]), fmaxf(sac1[2], sac1[3])));
        mx = fmaxf(mx, __shfl_xor(mx, 16));
        mx = fmaxf(mx, __shfl_xor(mx, 32));
        if (!__all(mx <= mreg + 11.5f)) {
            float mn = fmaxf(mreg, mx);
            float r  = EXP2(mreg - mn);
            lreg *= r;
            #pragma unroll
            for (int dt = 0; dt < 4; ++dt) oac[dt] *= r;
            mreg = mn;
        }
        float p0 = EXP2(sac0[0] - mreg), p1 = EXP2(sac0[1] - mreg);
        float p2 = EXP2(sac0[2] - mreg), p3 = EXP2(sac0[3] - mreg);
        float p4 = EXP2(sac1[0] - mreg), p5 = EXP2(sac1[1] - mreg);
        float p6 = EXP2(sac1[2] - mreg), p7 = EXP2(sac1[3] - mreg);
        float ls = ((p0 + p1) + (p2 + p3)) + ((p4 + p5) + (p6 + p7));
        ls += __shfl_xor(ls, 16);
        ls += __shfl_xor(ls, 32);
        lreg += ls;
        uint4 pb;
        pb.x = cvtpk(p0, p1);
        pb.y = cvtpk(p2, p3);
        pb.z = cvtpk(p4, p5);
        pb.w = cvtpk(p6, p7);

        uint4 vf0 = *(const uint4*)(bufc + vfoff[0]);
        uint4 vf1 = *(const uint4*)(bufc + vfoff[1]);
        uint4 vf2 = *(const uint4*)(bufc + vfoff[2]);
        uint4 vf3 = *(const uint4*)(bufc + vfoff[3]);
        __builtin_amdgcn_s_setprio(1);
        oac[0] = MFMA(BC8(vf0), BC8(pb), oac[0]);
        oac[1] = MFMA(BC8(vf1), BC8(pb), oac[1]);
        oac[2] = MFMA(BC8(vf2), BC8(pb), oac[2]);
        oac[3] = MFMA(BC8(vf3), BC8(pb), oac[3]);
        __builtin_amdgcn_s_setprio(0);
    };

    // prologue: stage tiles 0,1 into buf0,buf1
    STAGE(smem, 0);
    STAGE(smem + 32768, 1);
    __syncthreads();

    for (int i = 0; i < 16; ++i) {
        int kt = i << 1;
        int a = (i & 1) << 1;                        // compute pair: bufs a, a+1
        if (kt + 2 < 32) {
            STAGE(smem + (((a + 2) & 3) << 15), kt + 2);
            STAGE(smem + (((a + 3) & 3) << 15), kt + 3);
        }
        DOTILE(smem + (a << 15));                    // tile kt
        DOTILE(smem + ((a + 1) << 15));              // tile kt+1
        __syncthreads();
    }

    // ---- stats exchange: mlb/llb [16 waves][16 q] ----
    float* mlb = (float*)(smem + PREG);
    float* llb = (float*)(smem + PREG + 1024);
    if (lane < 16) {
        mlb[(w << 4) + lane] = mreg;
        llb[(w << 4) + lane] = lreg;
    }
    __syncthreads();

    int base = qg << 2;
    float m0 = mlb[((base + 0) << 4) + c], m1 = mlb[((base + 1) << 4) + c];
    float m2 = mlb[((base + 2) << 4) + c], m3 = mlb[((base + 3) << 4) + c];
    float M  = fmaxf(fmaxf(m0, m1), fmaxf(m2, m3));
    float a0 = EXP2(m0 - M), a1 = EXP2(m1 - M), a2 = EXP2(m2 - M), a3 = EXP2(m3 - M);
    float L  = a0 * llb[((base + 0) << 4) + c] + a1 * llb[((base + 1) << 4) + c]
             + a2 * llb[((base + 2) << 4) + c] + a3 * llb[((base + 3) << 4) + c];
    float aw = (ks == 0) ? a0 : (ks == 1) ? a1 : (ks == 2) ? a2 : a3;
    float fac = aw / L;
    #pragma unroll
    for (int dt = 0; dt < 4; ++dt) oac[dt] *= fac;

    // ---- accumulate scaled partials into Po f32 @0, rounds ks = 0,1,2 ----
    for (int r = 0; r < 3; ++r) {
        if (ks == r) {
            #pragma unroll
            for (int dt = 0; dt < 4; ++dt) {
                int q = (qg << 4) + c;
                int off = (q << 8) + ((((dt << 2) | g) ^ (q & 7)) << 4);
                f32x4 v = oac[dt];
                if (r > 0) v += *(const f32x4*)(smem + off);
                *(f32x4*)(smem + off) = v;
            }
        }
        __syncthreads();
    }
    // round 3: final add -> bf16 Pb @16384 ([64q][72] ushort, pitch 144B)
    ushort_t* Pb = (ushort_t*)(smem + 16384);
    if (ks == 3) {
        #pragma unroll
        for (int dt = 0; dt < 4; ++dt) {
            int q = (qg << 4) + c;
            int off = (q << 8) + ((((dt << 2) | g) ^ (q & 7)) << 4);
            f32x4 v = oac[dt] + *(const f32x4*)(smem + off);
            uint2 pk;
            pk.x = pk2(v[0], v[1]);
            pk.y = pk2(v[2], v[3]);
            *(uint2*)(Pb + q * 72 + (dt << 4) + (g << 2)) = pk;
        }
    }
    __syncthreads();

    // ---- fused outconv: out[o][q] = gamma*(Wa[o][:] . Pb[q][:] + ba[o]) ----
    const ushort_t* Wab = Wb + 24576;
    float gm = gamma[0];
    int ot = w >> 2, qt3 = w & 3;
    f32x4 acc2 = (f32x4){0.f,0.f,0.f,0.f};
    #pragma unroll
    for (int k2 = 0; k2 < 2; ++k2) {
        uint4 af  = *(const uint4*)(Wab + (((ot << 4) + c) << 6) + (k2 << 5) + (g << 3));
        uint4 pfq = *(const uint4*)((char*)Pb + (((qt3 << 4) + c)) * 144 + (k2 << 6) + (g << 4));
        acc2 = MFMA(BC8(af), BC8(pfq), acc2);
    }
    float* ob = out + (size_t)b * CO * NPIX + n0;
    #pragma unroll
    for (int r = 0; r < 4; ++r) {
        int o = (ot << 4) + (g << 2) + r;
        ob[(size_t)o * NPIX + (qt3 << 4) + c] = gm * (acc2[r] + ba[o]);
    }
}

extern "C" void kernel_launch(void* const* d_in, const int* in_sizes, int n_in,
                              void* d_out, int out_size, void* d_ws, size_t ws_size,
                              hipStream_t stream) {
    const float* x     = (const float*)d_in[0];
    const float* Wf    = (const float*)d_in[1];
    const float* bf_   = (const float*)d_in[2];
    const float* Wg    = (const float*)d_in[3];
    const float* bg_   = (const float*)d_in[4];
    const float* Wh    = (const float*)d_in[5];
    const float* bh_   = (const float*)d_in[6];
    const float* Wa    = (const float*)d_in[7];
    const float* ba    = (const float*)d_in[8];
    const float* gamma = (const float*)d_in[9];
    float* out = (float*)d_out;

    ushort_t* Wb = (ushort_t*)d_ws;                               // 57344 B
    const size_t matb = (size_t)BATCH * NPIX * CO;                // 1M elems
    ushort_t* Q = (ushort_t*)((char*)d_ws + 65536);               // 2 MB
    ushort_t* K = Q + matb;                                       // 2 MB
    ushort_t* V = K + matb;                                       // 2 MB (transposed, sigma-permuted)

    wconv_kernel<<<16, 256, 0, stream>>>(Wf, Wg, Wh, Wa, Wb);
    proj_kernel<<<BATCH * (NPIX / 64), 256, 0, stream>>>(x, Wb, bf_, bg_, bh_, Q, K, V);
    flash_kernel<<<BATCH * (NPIX / 64), 1024, 133120, stream>>>(Q, K, V, Wb, ba, gamma, out);
}

// Round 13
// 54.024 us; speedup vs baseline: 1.4944x; 1.0750x over previous
//
#include <hip/hip_runtime.h>
#include <math.h>

#define BATCH 4
#define CIN   128
#define CO    64
#define NPIX  4096
#define LOG2E 1.4426950408889634f

typedef unsigned int   uint_t;
typedef unsigned short ushort_t;
typedef __bf16 bfx8 __attribute__((ext_vector_type(8)));
typedef float  f32x4  __attribute__((ext_vector_type(4)));
typedef float  f32x16 __attribute__((ext_vector_type(16)));

#define MFMA(a,b,c)   __builtin_amdgcn_mfma_f32_16x16x32_bf16((a),(b),(c),0,0,0)
#define MFMA32(a,b,c) __builtin_amdgcn_mfma_f32_32x32x16_bf16((a),(b),(c),0,0,0)
#define BC8(x) __builtin_bit_cast(bfx8,(x))

#if __has_builtin(__builtin_amdgcn_exp2f)
#define EXP2(x) __builtin_amdgcn_exp2f(x)
#else
#define EXP2(x) exp2f(x)
#endif

static __device__ __forceinline__ ushort_t f2bf(float f) {
    uint_t u = __builtin_bit_cast(uint_t, f);
    u = (u + 0x7fffu + ((u >> 16) & 1u)) >> 16;   // RNE
    return (ushort_t)u;
}
static __device__ __forceinline__ float bf2f(ushort_t h) {
    return __builtin_bit_cast(float, (uint_t)h << 16);
}
static __device__ __forceinline__ uint_t pk2(float a, float b) {
    return (uint_t)f2bf(a) | ((uint_t)f2bf(b) << 16);
}
static __device__ __forceinline__ uint_t cvtpk(float lo, float hi) {
    uint_t r;
    asm("v_cvt_pk_bf16_f32 %0, %1, %2" : "=v"(r) : "v"(lo), "v"(hi));
    return r;
}
static __device__ __forceinline__ void gload16(const void* g, void* l) {
    __builtin_amdgcn_global_load_lds(
        (const __attribute__((address_space(1))) void*)g,
        (__attribute__((address_space(3))) void*)l, 16, 0, 0);
}

// ---------------- Kernel 0: convert Wf,Wg,Wh,Wa to bf16 in ws ----------------
__global__ __launch_bounds__(256) void wconv_kernel(
    const float* __restrict__ Wf, const float* __restrict__ Wg,
    const float* __restrict__ Wh, const float* __restrict__ Wa,
    ushort_t* __restrict__ Wb)
{
    int gid = blockIdx.x * 256 + threadIdx.x;
    for (int e = gid; e < 28672; e += 4096) {
        float v;
        if      (e < 8192)  v = Wf[e];
        else if (e < 16384) v = Wg[e - 8192];
        else if (e < 24576) v = Wh[e - 16384];
        else                v = Wa[e - 24576];
        Wb[e] = f2bf(v);
    }
}

// ---------------- Kernel 1: MFMA projections, LDS-free (verified R10; V now STRAIGHT) ----------------
__global__ __launch_bounds__(256) void proj_kernel(
    const float* __restrict__ x, const ushort_t* __restrict__ Wb,
    const float* __restrict__ bf_, const float* __restrict__ bg_, const float* __restrict__ bh_,
    ushort_t* __restrict__ Q, ushort_t* __restrict__ K, ushort_t* __restrict__ V)
{
    int bid = blockIdx.x, b = bid >> 6, n0 = (bid & 63) << 6, t = threadIdx.x;
    int w = t >> 6, lane = t & 63, cl = lane & 15, g = (lane >> 4) & 3;

    const float* xcol = x + (size_t)b * CIN * NPIX + n0 + (w << 4) + cl;

    uint4 aq[4], al[4];
    #pragma unroll
    for (int ks = 0; ks < 4; ++ks) {
        float v[8];
        #pragma unroll
        for (int j = 0; j < 8; ++j)
            v[j] = xcol[(size_t)((ks << 5) + (g << 3) + j) * NPIX];
        ushort_t hv[8];
        #pragma unroll
        for (int j = 0; j < 8; ++j) hv[j] = f2bf(v[j]);
        uint4 a, l;
        a.x = (uint_t)hv[0] | ((uint_t)hv[1] << 16);
        a.y = (uint_t)hv[2] | ((uint_t)hv[3] << 16);
        a.z = (uint_t)hv[4] | ((uint_t)hv[5] << 16);
        a.w = (uint_t)hv[6] | ((uint_t)hv[7] << 16);
        l.x = pk2(v[0] - bf2f(hv[0]), v[1] - bf2f(hv[1]));
        l.y = pk2(v[2] - bf2f(hv[2]), v[3] - bf2f(hv[3]));
        l.z = pk2(v[4] - bf2f(hv[4]), v[5] - bf2f(hv[5]));
        l.w = pk2(v[6] - bf2f(hv[6]), v[7] - bf2f(hv[7]));
        aq[ks] = a; al[ks] = l;
    }

    const float* bps[3] = {bf_, bg_, bh_};
    int nb = n0 + (w << 4);

    for (int p = 0; p < 3; ++p) {
        const ushort_t* Wp = Wb + p * 8192;
        float sc = (p == 0) ? LOG2E : 1.0f;    // fold log2e into Q for exp2 softmax
        f32x4 acc[4];
        #pragma unroll
        for (int ot = 0; ot < 4; ++ot) acc[ot] = (f32x4){0.f,0.f,0.f,0.f};
        #pragma unroll
        for (int ks = 0; ks < 4; ++ks) {
            #pragma unroll
            for (int ot = 0; ot < 4; ++ot) {
                uint4 bq = *(const uint4*)(Wp + (((ot << 4) + cl) << 7) + (ks << 5) + (g << 3));
                acc[ot] = MFMA(BC8(aq[ks]), BC8(bq), acc[ot]);
                acc[ot] = MFMA(BC8(al[ks]), BC8(bq), acc[ot]);
            }
        }
        if (p < 2) {
            ushort_t* dst = (p == 0 ? Q : K) + ((size_t)b * NPIX + nb) * CO;
            #pragma unroll
            for (int ot = 0; ot < 4; ++ot) {
                float bias = bps[p][(ot << 4) + cl];
                #pragma unroll
                for (int r = 0; r < 4; ++r)
                    dst[(size_t)((g << 2) + r) * CO + (ot << 4) + cl] = f2bf((acc[ot][r] + bias) * sc);
            }
        } else {
            #pragma unroll
            for (int ot = 0; ot < 4; ++ot) {
                float bias = bps[p][(ot << 4) + cl];
                uint2 pk;
                pk.x = pk2(acc[ot][0] + bias, acc[ot][1] + bias);
                pk.y = pk2(acc[ot][2] + bias, acc[ot][3] + bias);
                ushort_t* Vd = V + (size_t)b * CO * NPIX + (size_t)((ot << 4) + cl) * NPIX + nb + (g << 2);
                *(uint2*)Vd = pk;      // STRAIGHT order (32x32 path needs no sigma)
            }
        }
    }
}

// ---------------- Kernel 2: flash attention, 32x32 MFMA, register-P ----------------
// 256 blocks, 1024 thr = 16 waves = 2 q-halves (qh=w>>3, 32q) x 8 key-slices (ks=w&7, 32 keys).
// KV tile = 256 keys. QK^T: 4x mfma_32x32x16 with kappa-permuted A-rows (kappa = swap bits
// 2<->3 of row) so D reg p holds key 8*hi+p (kt0) / 16+8*hi+(p-8) (kt1) == B-frag order.
// PV: 4x mfma_32x32x16, V read straight. P never touches LDS.
// Dynamic LDS 135168B: buf[i] @ i*65536: K [256][64] swz ^key&7 (32K) | Vt [64][256] swz (32K)
//   stats @131072: mlb 2KB + llb 2KB. Epilogue overlays: Po f32 [64q][64d] swz @0; Pb @16384.
__global__ __launch_bounds__(1024, 4) void flash_kernel(
    const ushort_t* __restrict__ Q, const ushort_t* __restrict__ K,
    const ushort_t* __restrict__ V, const ushort_t* __restrict__ Wb,
    const float* __restrict__ ba, const float* __restrict__ gamma,
    float* __restrict__ out)
{
    extern __shared__ __align__(16) char smem[];

    int orig = blockIdx.x;
    int bid = ((orig & 7) << 5) | (orig >> 3);      // XCD swizzle: 2 XCDs per batch
    int b = bid >> 6, n0 = (bid & 63) << 6, t = threadIdx.x;
    int w = t >> 6, lane = t & 63;
    int qh = w >> 3, ks = w & 7;
    int ql = lane & 31, hi = lane >> 5;

    const ushort_t* Qb = Q + ((size_t)b * NPIX + n0) * CO;
    const ushort_t* Kb = K + (size_t)b * NPIX * CO;
    const ushort_t* Vb = V + (size_t)b * CO * NPIX;

    // Q B-fragments: col q = 32qh + ql, k(d) = 16m + 8hi + j
    int q = (qh << 5) + ql;
    uint4 qf[4];
    #pragma unroll
    for (int m = 0; m < 4; ++m)
        qf[m] = *(const uint4*)(Qb + q * CO + (m << 4) + (hi << 3));

    f32x16 oac0 = (f32x16)0.f, oac1 = (f32x16)0.f;  // O[d][q]: dh 0/1, row=(p&3)+8(p>>2)+4hi+32dh
    float mreg = -INFINITY, lreg = 0.f;

    // kappa-permuted K A-frag offsets: row r holds key kappa(r) = swap bits2<->3
    int kl = (ql & 19) | ((ql & 4) << 1) | ((ql & 8) >> 1);
    int key = (ks << 5) + kl;
    int koff[4];
    #pragma unroll
    for (int m = 0; m < 4; ++m)
        koff[m] = (key << 7) + (((((m << 1) | hi)) ^ (key & 7)) << 4);
    // V A-frag offsets: row d = 32dh + ql, k(key) = 32ks + 16kt + 8hi + j
    int voff[2][2];
    #pragma unroll
    for (int dh = 0; dh < 2; ++dh)
        #pragma unroll
        for (int kt = 0; kt < 2; ++kt) {
            int dv = (dh << 5) + ql;
            int slot = (((ks << 2) + (kt << 1) + hi)) ^ (dv & 7);
            voff[dh][kt] = 32768 + (dv << 9) + (slot << 4);
        }

    // stage 256-key tile: K 32KB + Vt 32KB; linear LDS dest, pre-swizzled global source
    auto STAGE = [&](char* buf, int kt) {
        #pragma unroll
        for (int i = 0; i < 2; ++i) {
            int cb = (i << 10) + (w << 6);           // wave-uniform chunk base
            int ci = cb | lane;                      // 0..2047
            int kk = ci >> 3, kc = (ci & 7) ^ (kk & 7);
            gload16(Kb + (size_t)((kt << 8) + kk) * CO + (kc << 3), buf + (cb << 4));
            int d = ci >> 5, vc = (ci & 31) ^ (d & 7);
            gload16(Vb + (size_t)d * NPIX + (kt << 8) + (vc << 3), buf + 32768 + (cb << 4));
        }
    };

    auto DOTILE = [&](char* bufc) {
        uint4 kf0 = *(const uint4*)(bufc + koff[0]);
        uint4 kf1 = *(const uint4*)(bufc + koff[1]);
        uint4 kf2 = *(const uint4*)(bufc + koff[2]);
        uint4 kf3 = *(const uint4*)(bufc + koff[3]);
        f32x16 s = (f32x16)0.f;
        __builtin_amdgcn_s_setprio(1);
        s = MFMA32(BC8(kf0), BC8(qf[0]), s);
        s = MFMA32(BC8(kf1), BC8(qf[1]), s);
        s = MFMA32(BC8(kf2), BC8(qf[2]), s);
        s = MFMA32(BC8(kf3), BC8(qf[3]), s);
        __builtin_amdgcn_s_setprio(0);

        // ---- online softmax: 16 scores/lane (half of 32 keys; partner lane^32 has rest) ----
        float mx = s[0];
        #pragma unroll
        for (int p = 1; p < 16; ++p) mx = fmaxf(mx, s[p]);
        mx = fmaxf(mx, __shfl_xor(mx, 32));
        if (!__all(mx <= mreg + 11.5f)) {
            float mn = fmaxf(mreg, mx);
            float r  = EXP2(mreg - mn);
            lreg *= r;
            oac0 *= r; oac1 *= r;
            mreg = mn;
        }
        float pv[16], ls = 0.f;
        #pragma unroll
        for (int p = 0; p < 16; ++p) { pv[p] = EXP2(s[p] - mreg); ls += pv[p]; }
        ls += __shfl_xor(ls, 32);
        lreg += ls;
        uint4 pb0, pb1;
        pb0.x = cvtpk(pv[0], pv[1]);  pb0.y = cvtpk(pv[2],  pv[3]);
        pb0.z = cvtpk(pv[4], pv[5]);  pb0.w = cvtpk(pv[6],  pv[7]);
        pb1.x = cvtpk(pv[8], pv[9]);  pb1.y = cvtpk(pv[10], pv[11]);
        pb1.z = cvtpk(pv[12], pv[13]); pb1.w = cvtpk(pv[14], pv[15]);

        uint4 vf00 = *(const uint4*)(bufc + voff[0][0]);
        uint4 vf01 = *(const uint4*)(bufc + voff[0][1]);
        uint4 vf10 = *(const uint4*)(bufc + voff[1][0]);
        uint4 vf11 = *(const uint4*)(bufc + voff[1][1]);
        __builtin_amdgcn_s_setprio(1);
        oac0 = MFMA32(BC8(vf00), BC8(pb0), oac0);
        oac0 = MFMA32(BC8(vf01), BC8(pb1), oac0);
        oac1 = MFMA32(BC8(vf10), BC8(pb0), oac1);
        oac1 = MFMA32(BC8(vf11), BC8(pb1), oac1);
        __builtin_amdgcn_s_setprio(0);
    };

    STAGE(smem, 0);
    __syncthreads();
    for (int i = 0; i < 16; ++i) {
        if (i + 1 < 16) STAGE(smem + (((i + 1) & 1) << 16), i + 1);
        DOTILE(smem + ((i & 1) << 16));
        __syncthreads();
    }

    // ---- stats exchange: mlb/llb [16 waves][32 q] ----
    float* mlb = (float*)(smem + 131072);
    float* llb = (float*)(smem + 133120);
    if (lane < 32) {
        mlb[(w << 5) + lane] = mreg;
        llb[(w << 5) + lane] = lreg;
    }
    __syncthreads();

    float M = -INFINITY;
    float mv[8];
    #pragma unroll
    for (int i = 0; i < 8; ++i) {
        mv[i] = mlb[(((qh << 3) + i) << 5) + ql];
        M = fmaxf(M, mv[i]);
    }
    float L = 0.f;
    #pragma unroll
    for (int i = 0; i < 8; ++i)
        L += EXP2(mv[i] - M) * llb[(((qh << 3) + i) << 5) + ql];
    float fac = EXP2(mreg - M) / L;
    oac0 *= fac; oac1 *= fac;

    // ---- accumulate scaled partials into Po f32 [64q][64d] swz @0, rounds ks = 0..6 ----
    for (int r = 0; r < 7; ++r) {
        if (ks == r) {
            #pragma unroll
            for (int dh = 0; dh < 2; ++dh)
                #pragma unroll
                for (int j2 = 0; j2 < 4; ++j2) {
                    int slot = (((j2 << 1) + hi + (dh << 3))) ^ (q & 7);
                    int off = (q << 8) + (slot << 4);
                    f32x4 v;
                    if (dh == 0) v = (f32x4){oac0[4*j2], oac0[4*j2+1], oac0[4*j2+2], oac0[4*j2+3]};
                    else         v = (f32x4){oac1[4*j2], oac1[4*j2+1], oac1[4*j2+2], oac1[4*j2+3]};
                    if (r > 0) v += *(const f32x4*)(smem + off);
                    *(f32x4*)(smem + off) = v;
                }
        }
        __syncthreads();
    }
    // final round: ks == 7 adds and converts -> Pb bf16 [64q][72] pitch 144B @16384
    ushort_t* Pb = (ushort_t*)(smem + 16384);
    if (ks == 7) {
        #pragma unroll
        for (int dh = 0; dh < 2; ++dh)
            #pragma unroll
            for (int j2 = 0; j2 < 4; ++j2) {
                int slot = (((j2 << 1) + hi + (dh << 3))) ^ (q & 7);
                int off = (q << 8) + (slot << 4);
                f32x4 v;
                if (dh == 0) v = (f32x4){oac0[4*j2], oac0[4*j2+1], oac0[4*j2+2], oac0[4*j2+3]};
                else         v = (f32x4){oac1[4*j2], oac1[4*j2+1], oac1[4*j2+2], oac1[4*j2+3]};
                v += *(const f32x4*)(smem + off);
                uint2 pk;
                pk.x = pk2(v[0], v[1]);
                pk.y = pk2(v[2], v[3]);
                // d0 = 8*j2 + 4*hi + 32*dh  -> byte offset d0*2
                *(uint2*)((char*)Pb + q * 144 + (j2 << 4) + (hi << 3) + (dh << 6)) = pk;
            }
    }
    __syncthreads();

    // ---- fused outconv (verified R12): out[o][q] = gamma*(Wa[o][:] . Pb[q][:] + ba[o]) ----
    {
        int c = lane & 15, g = (lane >> 4) & 3;
        const ushort_t* Wab = Wb + 24576;
        float gm = gamma[0];
        int ot = w >> 2, qt3 = w & 3;
        f32x4 acc2 = (f32x4){0.f,0.f,0.f,0.f};
        #pragma unroll
        for (int k2 = 0; k2 < 2; ++k2) {
            uint4 af  = *(const uint4*)(Wab + (((ot << 4) + c) << 6) + (k2 << 5) + (g << 3));
            uint4 pfq = *(const uint4*)((char*)Pb + (((qt3 << 4) + c)) * 144 + (k2 << 6) + (g << 4));
            acc2 = MFMA(BC8(af), BC8(pfq), acc2);
        }
        float* ob = out + (size_t)b * CO * NPIX + n0;
        #pragma unroll
        for (int r = 0; r < 4; ++r) {
            int o = (ot << 4) + (g << 2) + r;
            ob[(size_t)o * NPIX + (qt3 << 4) + c] = gm * (acc2[r] + ba[o]);
        }
    }
}

extern "C" void kernel_launch(void* const* d_in, const int* in_sizes, int n_in,
                              void* d_out, int out_size, void* d_ws, size_t ws_size,
                              hipStream_t stream) {
    const float* x     = (const float*)d_in[0];
    const float* Wf    = (const float*)d_in[1];
    const float* bf_   = (const float*)d_in[2];
    const float* Wg    = (const float*)d_in[3];
    const float* bg_   = (const float*)d_in[4];
    const float* Wh    = (const float*)d_in[5];
    const float* bh_   = (const float*)d_in[6];
    const float* Wa    = (const float*)d_in[7];
    const float* ba    = (const float*)d_in[8];
    const float* gamma = (const float*)d_in[9];
    float* out = (float*)d_out;

    ushort_t* Wb = (ushort_t*)d_ws;                               // 57344 B
    const size_t matb = (size_t)BATCH * NPIX * CO;                // 1M elems
    ushort_t* Q = (ushort_t*)((char*)d_ws + 65536);               // 2 MB
    ushort_t* K = Q + matb;                                       // 2 MB
    ushort_t* V = K + matb;                                       // 2 MB (transposed [B][64][N], straight)

    wconv_kernel<<<16, 256, 0, stream>>>(Wf, Wg, Wh, Wa, Wb);
    proj_kernel<<<BATCH * (NPIX / 64), 256, 0, stream>>>(x, Wb, bf_, bg_, bh_, Q, K, V);
    flash_kernel<<<BATCH * (NPIX / 64), 1024, 135168, stream>>>(Q, K, V, Wb, ba, gamma, out);
}